// Round 10
// baseline (440.403 us; speedup 1.0000x reference)
//
#include <hip/hip_runtime.h>
#include <hip/hip_bf16.h>

#define S_LEN 2048
#define HIDDEN 4096
#define NH 32
#define NKV 8
#define HD 128
#define NQKV 6144   // NH*HD + 2*NKV*HD

typedef __bf16 bf16_t;
typedef __bf16 bf16x8 __attribute__((ext_vector_type(8)));
typedef __bf16 bf16x4 __attribute__((ext_vector_type(4)));
typedef float f32x4 __attribute__((ext_vector_type(4)));

typedef __attribute__((address_space(1))) void gvoid;
typedef __attribute__((address_space(3))) void lvoid;

__device__ __forceinline__ void gload_lds16(const void* g, void* l) {
    __builtin_amdgcn_global_load_lds((gvoid*)g, (lvoid*)l, 16, 0, 0);
}

__device__ __forceinline__ float fast_exp2(float x) {
    return __builtin_amdgcn_exp2f(x);   // v_exp_f32 (2^x native)
}

// ---------------- cast fp32 -> bf16 (vectorized) ----------------
__global__ void cast_bf16_kernel(const float* __restrict__ in, bf16_t* __restrict__ out, int n4) {
    int stride = gridDim.x * blockDim.x;
    for (int idx = blockIdx.x * blockDim.x + threadIdx.x; idx < n4; idx += stride) {
        float4 v = ((const float4*)in)[idx];
        bf16x4 o;
        o.x = (bf16_t)v.x; o.y = (bf16_t)v.y; o.z = (bf16_t)v.z; o.w = (bf16_t)v.w;
        ((bf16x4*)out)[idx] = o;
    }
}

// ---------------- transpose + cast: in[R][C] fp32 (stride ldin) -> out[C][R] bf16 (stride ldout) ----------------
__global__ __launch_bounds__(256) void transpose_cast_kernel(const float* __restrict__ in,
                                                             bf16_t* __restrict__ out,
                                                             int ldin, int ldout) {
    __shared__ float t[32][33];
    int c0 = blockIdx.x * 32, r0 = blockIdx.y * 32;
    int tx = threadIdx.x, ty = threadIdx.y;
#pragma unroll
    for (int i = 0; i < 4; ++i)
        t[ty + i * 8][tx] = in[(size_t)(r0 + ty + i * 8) * ldin + c0 + tx];
    __syncthreads();
#pragma unroll
    for (int i = 0; i < 4; ++i)
        out[(size_t)(c0 + ty + i * 8) * ldout + r0 + tx] = (bf16_t)t[tx][ty + i * 8];
}

// ---------------- transpose bf16 -> bf16: in[R][C] (stride ldin) -> out[C][R] (stride ldout) ----------------
__global__ __launch_bounds__(256) void transpose_bf16_kernel(const bf16_t* __restrict__ in,
                                                             bf16_t* __restrict__ out,
                                                             int ldin, int ldout) {
    __shared__ float t[32][33];
    int c0 = blockIdx.x * 32, r0 = blockIdx.y * 32;
    int tx = threadIdx.x, ty = threadIdx.y;
#pragma unroll
    for (int i = 0; i < 4; ++i)
        t[ty + i * 8][tx] = (float)in[(size_t)(r0 + ty + i * 8) * ldin + c0 + tx];
    __syncthreads();
#pragma unroll
    for (int i = 0; i < 4; ++i)
        out[(size_t)(c0 + ty + i * 8) * ldout + r0 + tx] = (bf16_t)t[tx][ty + i * 8];
}

// ---------------- ring-3 counted-vmcnt GEMM: C[M][N] = A[M][K] @ Bt[N][K]^T ----------------
// (unchanged from round 9 — best measured GEMM structure)
template<typename OutT>
__global__ __launch_bounds__(512, 2) void gemm_ring_kernel(const bf16_t* __restrict__ A,
                                                           const bf16_t* __restrict__ Bt,
                                                           OutT* __restrict__ C,
                                                           int M, int N, int K) {
    __shared__ bf16_t As[3][128 * 32];
    __shared__ bf16_t Bs[3][256 * 32];
    const int tid = threadIdx.x;
    const int lane = tid & 63, w = tid >> 6;
    const int wm = w >> 2, wn = w & 3;
    const int g = lane >> 4, c16 = lane & 15;
    const int srow = lane >> 2;                              // row within a 16-row DMA instr
    const int scg = ((lane & 3) ^ ((lane >> 3) & 3)) * 8;    // pre-swizzled global chunk (elems)
    const int rdc = (g ^ ((c16 >> 1) & 3)) * 8;              // swizzled read chunk (elems)

    // XCD swizzle, bm-fastest
    const int nbm = M / 128;
    const int cpx = gridDim.x >> 3;
    const int bid = blockIdx.x;
    const int swz = (bid & 7) * cpx + (bid >> 3);
    const int bm = swz % nbm, bn = swz / nbm;

    const bf16_t* Ab = A + (size_t)(bm * 128) * K;
    const bf16_t* Bb = Bt + (size_t)(bn * 256) * K;

    auto stage = [&](int slot, int kt) {
        const bf16_t* Ak = Ab + (size_t)kt * 32;
        const bf16_t* Bk = Bb + (size_t)kt * 32;
        {   // A: 8 instrs total, 1 per wave: rows 16w..16w+15
            int rb = 16 * w;
            gload_lds16(Ak + (size_t)(rb + srow) * K + scg, &As[slot][rb * 32]);
        }
#pragma unroll
        for (int j = 0; j < 2; ++j) {   // B: 16 instrs, 2 per wave
            int rb = 32 * w + 16 * j;
            gload_lds16(Bk + (size_t)(rb + srow) * K + scg, &Bs[slot][rb * 32]);
        }
    };

    f32x4 acc[4][4];
#pragma unroll
    for (int i = 0; i < 4; ++i)
#pragma unroll
        for (int j = 0; j < 4; ++j)
            acc[i][j] = (f32x4){0.f, 0.f, 0.f, 0.f};

    const int NT = K / 32;
    stage(0, 0);
    stage(1, 1);

    int slot = 0, slot2 = 2;           // slot = t%3, slot2 = (t+2)%3
    for (int t = 0; t < NT; ++t) {
        asm volatile("s_waitcnt vmcnt(3)" ::: "memory");
        __builtin_amdgcn_s_barrier();
        __builtin_amdgcn_sched_barrier(0);
        __builtin_amdgcn_s_setprio(1);

        bf16x8 af[4], bf[4];
#pragma unroll
        for (int i = 0; i < 4; ++i) {
            int arow = wm * 64 + i * 16 + c16;
            af[i] = *(const bf16x8*)&As[slot][arow * 32 + rdc];
            int brow = wn * 64 + i * 16 + c16;
            bf[i] = *(const bf16x8*)&Bs[slot][brow * 32 + rdc];
        }
        int nk = t + 2;
        if (nk >= NT) nk -= NT;        // wrap-stage: keeps ledger uniform, never read
        stage(slot2, nk);

        // NO lgkmcnt(0) fence: compiler interleaves ds_reads with MFMAs (counted lgkmcnt)
#pragma unroll
        for (int i = 0; i < 4; ++i)
#pragma unroll
            for (int j = 0; j < 4; ++j)
                acc[i][j] = __builtin_amdgcn_mfma_f32_16x16x32_bf16(af[i], bf[j], acc[i][j], 0, 0, 0);
        __builtin_amdgcn_s_setprio(0);

        slot = (slot + 1) % 3;
        slot2 = (slot2 + 1) % 3;
    }

#pragma unroll
    for (int mi = 0; mi < 4; ++mi)
#pragma unroll
        for (int ni = 0; ni < 4; ++ni) {
            int col = bn * 256 + wn * 64 + ni * 16 + c16;
#pragma unroll
            for (int r = 0; r < 4; ++r) {
                int row = bm * 128 + wm * 64 + mi * 16 + g * 4 + r;
                C[(size_t)row * N + col] = (OutT)acc[mi][ni][r];
            }
        }
}

// ---------------- RoPE: in bf16 [S][ld] (head block at col h*128) -> out bf16 [H][S][128] ----------------
__global__ void rope_kernel(const bf16_t* __restrict__ in, bf16_t* __restrict__ out,
                            const int* __restrict__ pos, int H, int ld, float scale) {
    int idx = blockIdx.x * blockDim.x + threadIdx.x;
    int total = S_LEN * H * 64;
    if (idx >= total) return;
    int d = idx & 63;
    int h = (idx >> 6) % H;
    int s = idx / (64 * H);
    const bf16_t* base = in + (size_t)s * ld + h * HD;
    float x0 = (float)base[d], x1 = (float)base[d + 64];
    float p = (float)pos[s];
    float invf = fast_exp2(-0.20762050593046935f * (float)d);  // log2(10000)/64
    float f = p * invf;
    float sn, cs;
    __sincosf(f, &sn, &cs);
    float o0 = (x0 * cs - x1 * sn) * scale;
    float o1 = (x1 * cs + x0 * sn) * scale;
    bf16_t* ob = out + ((size_t)h * S_LEN + s) * HD;
    ob[d] = (bf16_t)o0;
    ob[d + 64] = (bf16_t)o1;
}

// ---------------- flash attention v2 ----------------
// K in LDS (dbuf, swizzled DMA); V in REGISTERS (issue-early, T14); softmax row-sum via
// ones-MFMA (matrix pipe, replaces 16 ds_bpermute shuffles); defer-max THR=8 (exp2 domain,
// skips rescale on most tiles). LDS 41.2KB -> 3 blocks/CU.
#define PLD 72
__global__ __launch_bounds__(256, 3) void attn_kernel(const bf16_t* __restrict__ Q,
                                                      const bf16_t* __restrict__ K,
                                                      const bf16_t* __restrict__ Vt,
                                                      bf16_t* __restrict__ O) {
    __shared__ bf16_t Ks[2][64 * 128];   // [kv row][d], swizzled chunks
    __shared__ bf16_t Pl[4][16 * PLD];
    const int tid = threadIdx.x;
    const int lane = tid & 63, w = tid >> 6;
    const int bid = blockIdx.x;
    const int h = bid & 31;
    const int x = bid >> 5;
    const int kv = h >> 2;               // N_REP = 4
    const int qb = x * 64 + w * 16;
    const int g = lane >> 4, c16 = lane & 15;
    const int c7 = c16 & 7;
    const bf16_t* Qh = Q + (size_t)h * S_LEN * HD;
    const bf16_t* Kh = K + (size_t)kv * S_LEN * HD;
    const bf16_t* Vh = Vt + (size_t)kv * HD * S_LEN;
    bf16_t* P = Pl[w];

    auto stageK = [&](int buf, int kb) {
        bf16_t* Kd = Ks[buf];
#pragma unroll
        for (int j = 0; j < 4; ++j) {
            int i = w * 4 + j;
            int row = 4 * i + (lane >> 4);
            int sc = (lane & 15) ^ (row & 7);
            gload_lds16(Kh + (size_t)(kb + row) * HD + sc * 8, Kd + i * 512);
        }
    };

    bf16x8 qf[4];
#pragma unroll
    for (int c = 0; c < 4; ++c)
        qf[c] = *(const bf16x8*)(Qh + (size_t)(qb + c16) * HD + c * 32 + g * 8);

    bf16x8 ones;
#pragma unroll
    for (int j = 0; j < 8; ++j) ones[j] = (bf16_t)1.0f;

    f32x4 acc_o[8];
#pragma unroll
    for (int dt = 0; dt < 8; ++dt) acc_o[dt] = (f32x4){0.f, 0.f, 0.f, 0.f};
    f32x4 acc_l = (f32x4){0.f, 0.f, 0.f, 0.f};
    float m[4] = {-1e30f, -1e30f, -1e30f, -1e30f};

    const int nkt = x + 1;               // KVBLK=64; diagonal tile is last
    stageK(0, 0);
    __syncthreads();
    int cur = 0;

    for (int kt = 0; kt < nkt; ++kt) {
        const int kb = kt * 64;
        if (kt + 1 < nkt) stageK(cur ^ 1, (kt + 1) * 64);
        // V half1 (dt 0..3) issue-early: latency hidden under QK^T + softmax
        bf16x8 v0[4][2];
#pragma unroll
        for (int dt = 0; dt < 4; ++dt) {
            const bf16_t* vrow = Vh + (size_t)(dt * 16 + c16) * S_LEN + kb;
            v0[dt][0] = *(const bf16x8*)(vrow + g * 8);
            v0[dt][1] = *(const bf16x8*)(vrow + 32 + g * 8);
        }
        const bf16_t* Kb = Ks[cur];
        const bool diag = (kt == nkt - 1);

        f32x4 sacc[4];
#pragma unroll
        for (int t = 0; t < 4; ++t) sacc[t] = (f32x4){0.f, 0.f, 0.f, 0.f};
#pragma unroll
        for (int t = 0; t < 4; ++t) {
            const bf16_t* krow = Kb + (t * 16 + c16) * 128;
#pragma unroll
            for (int cc = 0; cc < 4; ++cc) {
                bf16x8 kf = *(const bf16x8*)(krow + (((cc * 4 + g) ^ c7) * 8));
                sacc[t] = __builtin_amdgcn_mfma_f32_16x16x32_bf16(qf[cc], kf, sacc[t], 0, 0, 0);
            }
        }
        // masked scores -> p[][]; row max via 4 shuffles per row
        float p[4][4], mxr[4];
#pragma unroll
        for (int r = 0; r < 4; ++r) {
            int qq = qb + g * 4 + r;
#pragma unroll
            for (int t = 0; t < 4; ++t) {
                float sv = sacc[t][r];
                if (diag && (kb + t * 16 + c16 > qq)) sv = -1e30f;
                p[t][r] = sv;
            }
            float mx = fmaxf(fmaxf(p[0][r], p[1][r]), fmaxf(p[2][r], p[3][r]));
            mx = fmaxf(mx, __shfl_xor(mx, 1));
            mx = fmaxf(mx, __shfl_xor(mx, 2));
            mx = fmaxf(mx, __shfl_xor(mx, 4));
            mx = fmaxf(mx, __shfl_xor(mx, 8));
            mxr[r] = mx;
        }
        // defer-max: rescale only when some row grew past m+8 (exp2 domain => P <= 256)
        bool resc = false;
#pragma unroll
        for (int r = 0; r < 4; ++r) resc = resc || (mxr[r] > m[r] + 8.f);
        if (__any(resc)) {
#pragma unroll
            for (int r = 0; r < 4; ++r) {
                float mn = fmaxf(m[r], mxr[r]);
                float al = fast_exp2(m[r] - mn);
                m[r] = mn;
                acc_l[r] *= al;
#pragma unroll
                for (int dt = 0; dt < 8; ++dt) acc_o[dt][r] *= al;
            }
        }
#pragma unroll
        for (int r = 0; r < 4; ++r)
#pragma unroll
            for (int t = 0; t < 4; ++t)
                p[t][r] = fast_exp2(p[t][r] - m[r]);
        // P -> LDS (C-layout to A-layout redistribution), per-wave buffer
#pragma unroll
        for (int t = 0; t < 4; ++t)
#pragma unroll
            for (int r = 0; r < 4; ++r)
                P[(g * 4 + r) * PLD + t * 16 + c16] = (bf16_t)p[t][r];
        bf16x8 pf[2];
        pf[0] = *(const bf16x8*)(P + c16 * PLD + g * 8);
        pf[1] = *(const bf16x8*)(P + c16 * PLD + 32 + g * 8);
        // V half2 (dt 4..7): latency hidden under ones-MFMA + PV half1
        bf16x8 v1[4][2];
#pragma unroll
        for (int dt = 0; dt < 4; ++dt) {
            const bf16_t* vrow = Vh + (size_t)((dt + 4) * 16 + c16) * S_LEN + kb;
            v1[dt][0] = *(const bf16x8*)(vrow + g * 8);
            v1[dt][1] = *(const bf16x8*)(vrow + 32 + g * 8);
        }
        // row-sum on the matrix pipe: l += P @ ones
        acc_l = __builtin_amdgcn_mfma_f32_16x16x32_bf16(pf[0], ones, acc_l, 0, 0, 0);
        acc_l = __builtin_amdgcn_mfma_f32_16x16x32_bf16(pf[1], ones, acc_l, 0, 0, 0);
#pragma unroll
        for (int dt = 0; dt < 4; ++dt) {
            acc_o[dt] = __builtin_amdgcn_mfma_f32_16x16x32_bf16(pf[0], v0[dt][0], acc_o[dt], 0, 0, 0);
            acc_o[dt] = __builtin_amdgcn_mfma_f32_16x16x32_bf16(pf[1], v0[dt][1], acc_o[dt], 0, 0, 0);
        }
#pragma unroll
        for (int dt = 0; dt < 4; ++dt) {
            acc_o[dt + 4] = __builtin_amdgcn_mfma_f32_16x16x32_bf16(pf[0], v1[dt][0], acc_o[dt + 4], 0, 0, 0);
            acc_o[dt + 4] = __builtin_amdgcn_mfma_f32_16x16x32_bf16(pf[1], v1[dt][1], acc_o[dt + 4], 0, 0, 0);
        }
        __syncthreads();
        cur ^= 1;
    }
    float inv_l[4];
#pragma unroll
    for (int r = 0; r < 4; ++r) inv_l[r] = 1.f / acc_l[r];
#pragma unroll
    for (int dt = 0; dt < 8; ++dt)
#pragma unroll
        for (int r = 0; r < 4; ++r)
            O[(size_t)(qb + g * 4 + r) * HIDDEN + h * HD + dt * 16 + c16] =
                (bf16_t)(acc_o[dt][r] * inv_l[r]);
}

// ---------------- host ----------------
extern "C" void kernel_launch(void* const* d_in, const int* in_sizes, int n_in,
                              void* d_out, int out_size, void* d_ws, size_t ws_size,
                              hipStream_t stream) {
    const float* hs = (const float*)d_in[0];
    const float* Wq = (const float*)d_in[1];
    const float* Wk = (const float*)d_in[2];
    const float* Wv = (const float*)d_in[3];
    const float* Wo = (const float*)d_in[4];
    const int* pos = (const int*)d_in[6];
    float* out = (float*)d_out;

    char* ws = (char*)d_ws;
    size_t off = 0;
    auto alloc = [&](size_t bytes) -> void* {
        void* p = ws + off;
        off += (bytes + 255) & ~(size_t)255;
        return p;
    };
    bf16_t* hB    = (bf16_t*)alloc((size_t)S_LEN * HIDDEN * 2);
    bf16_t* WqkvT = (bf16_t*)alloc((size_t)NQKV * HIDDEN * 2);   // [6144][4096]
    bf16_t* WoT   = (bf16_t*)alloc((size_t)HIDDEN * HIDDEN * 2);
    bf16_t* QKV   = (bf16_t*)alloc((size_t)S_LEN * NQKV * 2);    // [2048][6144] bf16
    bf16_t* Qr    = (bf16_t*)alloc((size_t)NH * S_LEN * HD * 2);
    bf16_t* Kr    = (bf16_t*)alloc((size_t)NKV * S_LEN * HD * 2);
    bf16_t* Vt    = (bf16_t*)alloc((size_t)NKV * HD * S_LEN * 2);
    bf16_t* Oat   = (bf16_t*)alloc((size_t)S_LEN * HIDDEN * 2);

    dim3 tb(32, 8);
    // 1. cast hidden to bf16
    cast_bf16_kernel<<<2048, 256, 0, stream>>>(hs, hB, S_LEN * HIDDEN / 4);
    // 2. transpose-cast weights into fused [6144][4096]
    transpose_cast_kernel<<<dim3(HIDDEN / 32, HIDDEN / 32), tb, 0, stream>>>(Wq, WqkvT, HIDDEN, HIDDEN);
    transpose_cast_kernel<<<dim3(1024 / 32, HIDDEN / 32), tb, 0, stream>>>(Wk, WqkvT + (size_t)4096 * HIDDEN, 1024, HIDDEN);
    transpose_cast_kernel<<<dim3(1024 / 32, HIDDEN / 32), tb, 0, stream>>>(Wv, WqkvT + (size_t)5120 * HIDDEN, 1024, HIDDEN);
    transpose_cast_kernel<<<dim3(HIDDEN / 32, HIDDEN / 32), tb, 0, stream>>>(Wo, WoT, HIDDEN, HIDDEN);
    // 3. fused QKV projection -> bf16 [2048][6144], 384 blocks (full chip)
    gemm_ring_kernel<bf16_t><<<(S_LEN / 128) * (NQKV / 256), 512, 0, stream>>>(hB, WqkvT, QKV, S_LEN, NQKV, HIDDEN);
    // 4. RoPE; Q scale = log2(e)/sqrt(128) for exp2-domain softmax
    rope_kernel<<<(S_LEN * NH * 64 + 255) / 256, 256, 0, stream>>>(QKV, Qr, pos, NH, NQKV, 0.1275174310f);
    rope_kernel<<<(S_LEN * NKV * 64 + 255) / 256, 256, 0, stream>>>(QKV + 4096, Kr, pos, NKV, NQKV, 1.0f);
    // 5. V transpose: bf16 [S][1024] (stride 6144) -> [1024][2048] == [NKV][128][S]
    transpose_bf16_kernel<<<dim3(1024 / 32, S_LEN / 32), tb, 0, stream>>>(QKV + 5120, Vt, NQKV, S_LEN);
    // 6. flash attention
    attn_kernel<<<1024, 256, 0, stream>>>(Qr, Kr, Vt, Oat);
    // 7. output projection (fp32 out), 256 blocks
    gemm_ring_kernel<float><<<(S_LEN / 128) * (HIDDEN / 256), 512, 0, stream>>>(Oat, WoT, out, S_LEN, HIDDEN, HIDDEN);
}

// Round 11
// 385.441 us; speedup vs baseline: 1.1426x; 1.1426x over previous
//
#include <hip/hip_runtime.h>
#include <hip/hip_bf16.h>

#define S_LEN 2048
#define HIDDEN 4096
#define NH 32
#define NKV 8
#define HD 128
#define NQKV 6144   // NH*HD + 2*NKV*HD

typedef __bf16 bf16_t;
typedef __bf16 bf16x8 __attribute__((ext_vector_type(8)));
typedef __bf16 bf16x4 __attribute__((ext_vector_type(4)));
typedef float f32x4 __attribute__((ext_vector_type(4)));

typedef __attribute__((address_space(1))) void gvoid;
typedef __attribute__((address_space(3))) void lvoid;

__device__ __forceinline__ void gload_lds16(const void* g, void* l) {
    __builtin_amdgcn_global_load_lds((gvoid*)g, (lvoid*)l, 16, 0, 0);
}

__device__ __forceinline__ float fast_exp2(float x) {
    return __builtin_amdgcn_exp2f(x);   // v_exp_f32 (2^x native)
}

// ---------------- cast fp32 -> bf16 (vectorized) ----------------
__global__ void cast_bf16_kernel(const float* __restrict__ in, bf16_t* __restrict__ out, int n4) {
    int stride = gridDim.x * blockDim.x;
    for (int idx = blockIdx.x * blockDim.x + threadIdx.x; idx < n4; idx += stride) {
        float4 v = ((const float4*)in)[idx];
        bf16x4 o;
        o.x = (bf16_t)v.x; o.y = (bf16_t)v.y; o.z = (bf16_t)v.z; o.w = (bf16_t)v.w;
        ((bf16x4*)out)[idx] = o;
    }
}

// ---------------- transpose + cast: in[R][C] fp32 (stride ldin) -> out[C][R] bf16 (stride ldout) ----------------
__global__ __launch_bounds__(256) void transpose_cast_kernel(const float* __restrict__ in,
                                                             bf16_t* __restrict__ out,
                                                             int ldin, int ldout) {
    __shared__ float t[32][33];
    int c0 = blockIdx.x * 32, r0 = blockIdx.y * 32;
    int tx = threadIdx.x, ty = threadIdx.y;
#pragma unroll
    for (int i = 0; i < 4; ++i)
        t[ty + i * 8][tx] = in[(size_t)(r0 + ty + i * 8) * ldin + c0 + tx];
    __syncthreads();
#pragma unroll
    for (int i = 0; i < 4; ++i)
        out[(size_t)(c0 + ty + i * 8) * ldout + r0 + tx] = (bf16_t)t[tx][ty + i * 8];
}

// ---------------- transpose bf16 -> bf16: in[R][C] (stride ldin) -> out[C][R] (stride ldout) ----------------
__global__ __launch_bounds__(256) void transpose_bf16_kernel(const bf16_t* __restrict__ in,
                                                             bf16_t* __restrict__ out,
                                                             int ldin, int ldout) {
    __shared__ float t[32][33];
    int c0 = blockIdx.x * 32, r0 = blockIdx.y * 32;
    int tx = threadIdx.x, ty = threadIdx.y;
#pragma unroll
    for (int i = 0; i < 4; ++i)
        t[ty + i * 8][tx] = (float)in[(size_t)(r0 + ty + i * 8) * ldin + c0 + tx];
    __syncthreads();
#pragma unroll
    for (int i = 0; i < 4; ++i)
        out[(size_t)(c0 + ty + i * 8) * ldout + r0 + tx] = (bf16_t)t[tx][ty + i * 8];
}

// ---------------- ring-3 counted-vmcnt GEMM: C[M][N] = A[M][K] @ Bt[N][K]^T ----------------
// (unchanged — best measured GEMM structure)
template<typename OutT>
__global__ __launch_bounds__(512, 2) void gemm_ring_kernel(const bf16_t* __restrict__ A,
                                                           const bf16_t* __restrict__ Bt,
                                                           OutT* __restrict__ C,
                                                           int M, int N, int K) {
    __shared__ bf16_t As[3][128 * 32];
    __shared__ bf16_t Bs[3][256 * 32];
    const int tid = threadIdx.x;
    const int lane = tid & 63, w = tid >> 6;
    const int wm = w >> 2, wn = w & 3;
    const int g = lane >> 4, c16 = lane & 15;
    const int srow = lane >> 2;                              // row within a 16-row DMA instr
    const int scg = ((lane & 3) ^ ((lane >> 3) & 3)) * 8;    // pre-swizzled global chunk (elems)
    const int rdc = (g ^ ((c16 >> 1) & 3)) * 8;              // swizzled read chunk (elems)

    // XCD swizzle, bm-fastest
    const int nbm = M / 128;
    const int cpx = gridDim.x >> 3;
    const int bid = blockIdx.x;
    const int swz = (bid & 7) * cpx + (bid >> 3);
    const int bm = swz % nbm, bn = swz / nbm;

    const bf16_t* Ab = A + (size_t)(bm * 128) * K;
    const bf16_t* Bb = Bt + (size_t)(bn * 256) * K;

    auto stage = [&](int slot, int kt) {
        const bf16_t* Ak = Ab + (size_t)kt * 32;
        const bf16_t* Bk = Bb + (size_t)kt * 32;
        {   // A: 8 instrs total, 1 per wave: rows 16w..16w+15
            int rb = 16 * w;
            gload_lds16(Ak + (size_t)(rb + srow) * K + scg, &As[slot][rb * 32]);
        }
#pragma unroll
        for (int j = 0; j < 2; ++j) {   // B: 16 instrs, 2 per wave
            int rb = 32 * w + 16 * j;
            gload_lds16(Bk + (size_t)(rb + srow) * K + scg, &Bs[slot][rb * 32]);
        }
    };

    f32x4 acc[4][4];
#pragma unroll
    for (int i = 0; i < 4; ++i)
#pragma unroll
        for (int j = 0; j < 4; ++j)
            acc[i][j] = (f32x4){0.f, 0.f, 0.f, 0.f};

    const int NT = K / 32;
    stage(0, 0);
    stage(1, 1);

    int slot = 0, slot2 = 2;           // slot = t%3, slot2 = (t+2)%3
    for (int t = 0; t < NT; ++t) {
        asm volatile("s_waitcnt vmcnt(3)" ::: "memory");
        __builtin_amdgcn_s_barrier();
        __builtin_amdgcn_sched_barrier(0);
        __builtin_amdgcn_s_setprio(1);

        bf16x8 af[4], bf[4];
#pragma unroll
        for (int i = 0; i < 4; ++i) {
            int arow = wm * 64 + i * 16 + c16;
            af[i] = *(const bf16x8*)&As[slot][arow * 32 + rdc];
            int brow = wn * 64 + i * 16 + c16;
            bf[i] = *(const bf16x8*)&Bs[slot][brow * 32 + rdc];
        }
        int nk = t + 2;
        if (nk >= NT) nk -= NT;        // wrap-stage: keeps ledger uniform, never read
        stage(slot2, nk);

        // NO lgkmcnt(0) fence: compiler interleaves ds_reads with MFMAs (counted lgkmcnt)
#pragma unroll
        for (int i = 0; i < 4; ++i)
#pragma unroll
            for (int j = 0; j < 4; ++j)
                acc[i][j] = __builtin_amdgcn_mfma_f32_16x16x32_bf16(af[i], bf[j], acc[i][j], 0, 0, 0);
        __builtin_amdgcn_s_setprio(0);

        slot = (slot + 1) % 3;
        slot2 = (slot2 + 1) % 3;
    }

#pragma unroll
    for (int mi = 0; mi < 4; ++mi)
#pragma unroll
        for (int ni = 0; ni < 4; ++ni) {
            int col = bn * 256 + wn * 64 + ni * 16 + c16;
#pragma unroll
            for (int r = 0; r < 4; ++r) {
                int row = bm * 128 + wm * 64 + mi * 16 + g * 4 + r;
                C[(size_t)row * N + col] = (OutT)acc[mi][ni][r];
            }
        }
}

// ---------------- RoPE: in bf16 [S][ld] (head block at col h*128) -> out bf16 [H][S][128] ----------------
__global__ void rope_kernel(const bf16_t* __restrict__ in, bf16_t* __restrict__ out,
                            const int* __restrict__ pos, int H, int ld, float scale) {
    int idx = blockIdx.x * blockDim.x + threadIdx.x;
    int total = S_LEN * H * 64;
    if (idx >= total) return;
    int d = idx & 63;
    int h = (idx >> 6) % H;
    int s = idx / (64 * H);
    const bf16_t* base = in + (size_t)s * ld + h * HD;
    float x0 = (float)base[d], x1 = (float)base[d + 64];
    float p = (float)pos[s];
    float invf = fast_exp2(-0.20762050593046935f * (float)d);  // log2(10000)/64
    float f = p * invf;
    float sn, cs;
    __sincosf(f, &sn, &cs);
    float o0 = (x0 * cs - x1 * sn) * scale;
    float o1 = (x1 * cs + x0 * sn) * scale;
    bf16_t* ob = out + ((size_t)h * S_LEN + s) * HD;
    ob[d] = (bf16_t)o0;
    ob[d + 64] = (bf16_t)o1;
}

// ---------------- flash attention (round-9 staging + ones-MFMA sum + defer-max) ----------------
// K and V LDS-staged (dbuf, swizzled DMA, shared by all 4 waves — round-9 structure).
// Softmax: row-max via 4 shuffles/row; row-SUM on the matrix pipe (P @ ones into acc_l);
// defer-max THR=8 in exp2 domain (P <= 256, fp32 accum safe) skips the rescale pass.
#define PLD 68   // P row stride: 136B -> g-groups hit distinct banks (write 2-way only)
__global__ __launch_bounds__(256) void attn_kernel(const bf16_t* __restrict__ Q,
                                                   const bf16_t* __restrict__ K,
                                                   const bf16_t* __restrict__ Vt,
                                                   bf16_t* __restrict__ O) {
    __shared__ bf16_t Ks[2][64 * 128];   // [kv row][d], swizzled chunks
    __shared__ bf16_t Vs[2][128 * 64];   // [d][kv], swizzled chunks
    __shared__ bf16_t Pl[4][16 * PLD];
    const int tid = threadIdx.x;
    const int lane = tid & 63, w = tid >> 6;
    const int bid = blockIdx.x;
    const int h = bid & 31;
    const int x = bid >> 5;
    const int kv = h >> 2;               // N_REP = 4
    const int qb = x * 64 + w * 16;
    const int g = lane >> 4, c16 = lane & 15;
    const int c7 = c16 & 7;
    const bf16_t* Qh = Q + (size_t)h * S_LEN * HD;
    const bf16_t* Kh = K + (size_t)kv * S_LEN * HD;
    const bf16_t* Vh = Vt + (size_t)kv * HD * S_LEN;
    bf16_t* P = Pl[w];

    auto stage = [&](int buf, int kb) {
        bf16_t* Kd = Ks[buf];
        bf16_t* Vd = Vs[buf];
#pragma unroll
        for (int j = 0; j < 4; ++j) {
            int i = w * 4 + j;
            {   // K: instr covers 4 rows of 256B; lane l -> row 4i+(l>>4), chunk l&15
                int row = 4 * i + (lane >> 4);
                int sc = (lane & 15) ^ (row & 7);
                gload_lds16(Kh + (size_t)(kb + row) * HD + sc * 8, Kd + i * 512);
            }
            {   // V: instr covers 8 rows of 128B; lane l -> row 8i+(l>>3), chunk l&7
                int row = 8 * i + (lane >> 3);
                int sc = (lane & 7) ^ ((lane >> 3) & 7);
                gload_lds16(Vh + (size_t)row * S_LEN + kb + sc * 8, Vd + i * 512);
            }
        }
    };

    bf16x8 qf[4];
#pragma unroll
    for (int c = 0; c < 4; ++c)
        qf[c] = *(const bf16x8*)(Qh + (size_t)(qb + c16) * HD + c * 32 + g * 8);

    bf16x8 ones;
#pragma unroll
    for (int j = 0; j < 8; ++j) ones[j] = (bf16_t)1.0f;

    f32x4 acc_o[8];
#pragma unroll
    for (int dt = 0; dt < 8; ++dt) acc_o[dt] = (f32x4){0.f, 0.f, 0.f, 0.f};
    f32x4 acc_l = (f32x4){0.f, 0.f, 0.f, 0.f};
    float m[4] = {-1e30f, -1e30f, -1e30f, -1e30f};

    const int nkt = x + 1;               // KVBLK=64; diagonal tile is last
    stage(0, 0);
    __syncthreads();
    int cur = 0;

    for (int kt = 0; kt < nkt; ++kt) {
        if (kt + 1 < nkt) stage(cur ^ 1, (kt + 1) * 64);
        const int kb = kt * 64;
        const bf16_t* Kb = Ks[cur];
        const bf16_t* Vb = Vs[cur];
        const bool diag = (kt == nkt - 1);

        f32x4 sacc[4];
#pragma unroll
        for (int t = 0; t < 4; ++t) sacc[t] = (f32x4){0.f, 0.f, 0.f, 0.f};
#pragma unroll
        for (int t = 0; t < 4; ++t) {
            const bf16_t* krow = Kb + (t * 16 + c16) * 128;
#pragma unroll
            for (int cc = 0; cc < 4; ++cc) {
                bf16x8 kf = *(const bf16x8*)(krow + (((cc * 4 + g) ^ c7) * 8));
                sacc[t] = __builtin_amdgcn_mfma_f32_16x16x32_bf16(qf[cc], kf, sacc[t], 0, 0, 0);
            }
        }
        float p[4][4], mxr[4];
#pragma unroll
        for (int r = 0; r < 4; ++r) {
            int qq = qb + g * 4 + r;
#pragma unroll
            for (int t = 0; t < 4; ++t) {
                float sv = sacc[t][r];
                if (diag && (kb + t * 16 + c16 > qq)) sv = -1e30f;
                p[t][r] = sv;
            }
            float mx = fmaxf(fmaxf(p[0][r], p[1][r]), fmaxf(p[2][r], p[3][r]));
            mx = fmaxf(mx, __shfl_xor(mx, 1));
            mx = fmaxf(mx, __shfl_xor(mx, 2));
            mx = fmaxf(mx, __shfl_xor(mx, 4));
            mx = fmaxf(mx, __shfl_xor(mx, 8));
            mxr[r] = mx;
        }
        // defer-max: rescale only when a row's max grew past m+8 (exp2 domain => P <= 256)
        bool resc = false;
#pragma unroll
        for (int r = 0; r < 4; ++r) resc = resc || (mxr[r] > m[r] + 8.f);
        if (__any(resc)) {
#pragma unroll
            for (int r = 0; r < 4; ++r) {
                float mn = fmaxf(m[r], mxr[r]);
                float al = fast_exp2(m[r] - mn);
                m[r] = mn;
                acc_l[r] *= al;
#pragma unroll
                for (int dt = 0; dt < 8; ++dt) acc_o[dt][r] *= al;
            }
        }
#pragma unroll
        for (int r = 0; r < 4; ++r)
#pragma unroll
            for (int t = 0; t < 4; ++t)
                p[t][r] = fast_exp2(p[t][r] - m[r]);
        // P -> LDS (C-layout to A-layout redistribution), per-wave buffer: in-wave dep only
#pragma unroll
        for (int t = 0; t < 4; ++t)
#pragma unroll
            for (int r = 0; r < 4; ++r)
                P[(g * 4 + r) * PLD + t * 16 + c16] = (bf16_t)p[t][r];
        bf16x8 pf[2];
        pf[0] = *(const bf16x8*)(P + c16 * PLD + g * 8);
        pf[1] = *(const bf16x8*)(P + c16 * PLD + 32 + g * 8);
        // row-sum on the matrix pipe: l += P @ ones (replaces 16 sum-shuffles)
        acc_l = __builtin_amdgcn_mfma_f32_16x16x32_bf16(pf[0], ones, acc_l, 0, 0, 0);
        acc_l = __builtin_amdgcn_mfma_f32_16x16x32_bf16(pf[1], ones, acc_l, 0, 0, 0);
#pragma unroll
        for (int dt = 0; dt < 8; ++dt) {
            const bf16_t* vrow = Vb + (dt * 16 + c16) * 64;
            bf16x8 vf0 = *(const bf16x8*)(vrow + ((g ^ c7) * 8));
            bf16x8 vf1 = *(const bf16x8*)(vrow + (((4 + g) ^ c7) * 8));
            acc_o[dt] = __builtin_amdgcn_mfma_f32_16x16x32_bf16(pf[0], vf0, acc_o[dt], 0, 0, 0);
            acc_o[dt] = __builtin_amdgcn_mfma_f32_16x16x32_bf16(pf[1], vf1, acc_o[dt], 0, 0, 0);
        }
        __syncthreads();
        cur ^= 1;
    }
    float inv_l[4];
#pragma unroll
    for (int r = 0; r < 4; ++r) inv_l[r] = 1.f / acc_l[r];
#pragma unroll
    for (int dt = 0; dt < 8; ++dt)
#pragma unroll
        for (int r = 0; r < 4; ++r)
            O[(size_t)(qb + g * 4 + r) * HIDDEN + h * HD + dt * 16 + c16] =
                (bf16_t)(acc_o[dt][r] * inv_l[r]);
}

// ---------------- host ----------------
extern "C" void kernel_launch(void* const* d_in, const int* in_sizes, int n_in,
                              void* d_out, int out_size, void* d_ws, size_t ws_size,
                              hipStream_t stream) {
    const float* hs = (const float*)d_in[0];
    const float* Wq = (const float*)d_in[1];
    const float* Wk = (const float*)d_in[2];
    const float* Wv = (const float*)d_in[3];
    const float* Wo = (const float*)d_in[4];
    const int* pos = (const int*)d_in[6];
    float* out = (float*)d_out;

    char* ws = (char*)d_ws;
    size_t off = 0;
    auto alloc = [&](size_t bytes) -> void* {
        void* p = ws + off;
        off += (bytes + 255) & ~(size_t)255;
        return p;
    };
    bf16_t* hB    = (bf16_t*)alloc((size_t)S_LEN * HIDDEN * 2);
    bf16_t* WqkvT = (bf16_t*)alloc((size_t)NQKV * HIDDEN * 2);   // [6144][4096]
    bf16_t* WoT   = (bf16_t*)alloc((size_t)HIDDEN * HIDDEN * 2);
    bf16_t* QKV   = (bf16_t*)alloc((size_t)S_LEN * NQKV * 2);    // [2048][6144] bf16
    bf16_t* Qr    = (bf16_t*)alloc((size_t)NH * S_LEN * HD * 2);
    bf16_t* Kr    = (bf16_t*)alloc((size_t)NKV * S_LEN * HD * 2);
    bf16_t* Vt    = (bf16_t*)alloc((size_t)NKV * HD * S_LEN * 2);
    bf16_t* Oat   = (bf16_t*)alloc((size_t)S_LEN * HIDDEN * 2);

    dim3 tb(32, 8);
    // 1. cast hidden to bf16
    cast_bf16_kernel<<<2048, 256, 0, stream>>>(hs, hB, S_LEN * HIDDEN / 4);
    // 2. transpose-cast weights into fused [6144][4096]
    transpose_cast_kernel<<<dim3(HIDDEN / 32, HIDDEN / 32), tb, 0, stream>>>(Wq, WqkvT, HIDDEN, HIDDEN);
    transpose_cast_kernel<<<dim3(1024 / 32, HIDDEN / 32), tb, 0, stream>>>(Wk, WqkvT + (size_t)4096 * HIDDEN, 1024, HIDDEN);
    transpose_cast_kernel<<<dim3(1024 / 32, HIDDEN / 32), tb, 0, stream>>>(Wv, WqkvT + (size_t)5120 * HIDDEN, 1024, HIDDEN);
    transpose_cast_kernel<<<dim3(HIDDEN / 32, HIDDEN / 32), tb, 0, stream>>>(Wo, WoT, HIDDEN, HIDDEN);
    // 3. fused QKV projection -> bf16 [2048][6144], 384 blocks (full chip)
    gemm_ring_kernel<bf16_t><<<(S_LEN / 128) * (NQKV / 256), 512, 0, stream>>>(hB, WqkvT, QKV, S_LEN, NQKV, HIDDEN);
    // 4. RoPE; Q scale = log2(e)/sqrt(128) for exp2-domain softmax
    rope_kernel<<<(S_LEN * NH * 64 + 255) / 256, 256, 0, stream>>>(QKV, Qr, pos, NH, NQKV, 0.1275174310f);
    rope_kernel<<<(S_LEN * NKV * 64 + 255) / 256, 256, 0, stream>>>(QKV + 4096, Kr, pos, NKV, NQKV, 1.0f);
    // 5. V transpose: bf16 [S][1024] (stride 6144) -> [1024][2048] == [NKV][128][S]
    transpose_bf16_kernel<<<dim3(1024 / 32, S_LEN / 32), tb, 0, stream>>>(QKV + 5120, Vt, NQKV, S_LEN);
    // 6. flash attention
    attn_kernel<<<1024, 256, 0, stream>>>(Qr, Kr, Vt, Oat);
    // 7. output projection (fp32 out), 256 blocks
    gemm_ring_kernel<float><<<(S_LEN / 128) * (HIDDEN / 256), 512, 0, stream>>>(Oat, WoT, out, S_LEN, HIDDEN, HIDDEN);
}

// Round 12
// 380.894 us; speedup vs baseline: 1.1562x; 1.0119x over previous
//
#include <hip/hip_runtime.h>
#include <hip/hip_bf16.h>

#define S_LEN 2048
#define HIDDEN 4096
#define NH 32
#define NKV 8
#define HD 128
#define NQKV 6144   // NH*HD + 2*NKV*HD

typedef __bf16 bf16_t;
typedef __bf16 bf16x8 __attribute__((ext_vector_type(8)));
typedef __bf16 bf16x4 __attribute__((ext_vector_type(4)));
typedef float f32x4 __attribute__((ext_vector_type(4)));

typedef __attribute__((address_space(1))) void gvoid;
typedef __attribute__((address_space(3))) void lvoid;

__device__ __forceinline__ void gload_lds16(const void* g, void* l) {
    __builtin_amdgcn_global_load_lds((gvoid*)g, (lvoid*)l, 16, 0, 0);
}

__device__ __forceinline__ float fast_exp2(float x) {
    return __builtin_amdgcn_exp2f(x);   // v_exp_f32 (2^x native)
}

// ---------------- cast fp32 -> bf16 (vectorized) ----------------
__global__ void cast_bf16_kernel(const float* __restrict__ in, bf16_t* __restrict__ out, int n4) {
    int stride = gridDim.x * blockDim.x;
    for (int idx = blockIdx.x * blockDim.x + threadIdx.x; idx < n4; idx += stride) {
        float4 v = ((const float4*)in)[idx];
        bf16x4 o;
        o.x = (bf16_t)v.x; o.y = (bf16_t)v.y; o.z = (bf16_t)v.z; o.w = (bf16_t)v.w;
        ((bf16x4*)out)[idx] = o;
    }
}

// ---------------- transpose + cast: in[R][C] fp32 (stride ldin) -> out[C][R] bf16 (stride ldout) ----------------
__global__ __launch_bounds__(256) void transpose_cast_kernel(const float* __restrict__ in,
                                                             bf16_t* __restrict__ out,
                                                             int ldin, int ldout) {
    __shared__ float t[32][33];
    int c0 = blockIdx.x * 32, r0 = blockIdx.y * 32;
    int tx = threadIdx.x, ty = threadIdx.y;
#pragma unroll
    for (int i = 0; i < 4; ++i)
        t[ty + i * 8][tx] = in[(size_t)(r0 + ty + i * 8) * ldin + c0 + tx];
    __syncthreads();
#pragma unroll
    for (int i = 0; i < 4; ++i)
        out[(size_t)(c0 + ty + i * 8) * ldout + r0 + tx] = (bf16_t)t[tx][ty + i * 8];
}

// ---------------- transpose bf16 -> bf16: in[R][C] (stride ldin) -> out[C][R] (stride ldout) ----------------
__global__ __launch_bounds__(256) void transpose_bf16_kernel(const bf16_t* __restrict__ in,
                                                             bf16_t* __restrict__ out,
                                                             int ldin, int ldout) {
    __shared__ float t[32][33];
    int c0 = blockIdx.x * 32, r0 = blockIdx.y * 32;
    int tx = threadIdx.x, ty = threadIdx.y;
#pragma unroll
    for (int i = 0; i < 4; ++i)
        t[ty + i * 8][tx] = (float)in[(size_t)(r0 + ty + i * 8) * ldin + c0 + tx];
    __syncthreads();
#pragma unroll
    for (int i = 0; i < 4; ++i)
        out[(size_t)(c0 + ty + i * 8) * ldout + r0 + tx] = (bf16_t)t[tx][ty + i * 8];
}

// ---------------- ring-3 counted-vmcnt GEMM: C[M][N] = A[M][K] @ Bt[N][K]^T ----------------
// (unchanged — best measured GEMM structure)
template<typename OutT>
__global__ __launch_bounds__(512, 2) void gemm_ring_kernel(const bf16_t* __restrict__ A,
                                                           const bf16_t* __restrict__ Bt,
                                                           OutT* __restrict__ C,
                                                           int M, int N, int K) {
    __shared__ bf16_t As[3][128 * 32];
    __shared__ bf16_t Bs[3][256 * 32];
    const int tid = threadIdx.x;
    const int lane = tid & 63, w = tid >> 6;
    const int wm = w >> 2, wn = w & 3;
    const int g = lane >> 4, c16 = lane & 15;
    const int srow = lane >> 2;                              // row within a 16-row DMA instr
    const int scg = ((lane & 3) ^ ((lane >> 3) & 3)) * 8;    // pre-swizzled global chunk (elems)
    const int rdc = (g ^ ((c16 >> 1) & 3)) * 8;              // swizzled read chunk (elems)

    // XCD swizzle, bm-fastest
    const int nbm = M / 128;
    const int cpx = gridDim.x >> 3;
    const int bid = blockIdx.x;
    const int swz = (bid & 7) * cpx + (bid >> 3);
    const int bm = swz % nbm, bn = swz / nbm;

    const bf16_t* Ab = A + (size_t)(bm * 128) * K;
    const bf16_t* Bb = Bt + (size_t)(bn * 256) * K;

    auto stage = [&](int slot, int kt) {
        const bf16_t* Ak = Ab + (size_t)kt * 32;
        const bf16_t* Bk = Bb + (size_t)kt * 32;
        {   // A: 8 instrs total, 1 per wave: rows 16w..16w+15
            int rb = 16 * w;
            gload_lds16(Ak + (size_t)(rb + srow) * K + scg, &As[slot][rb * 32]);
        }
#pragma unroll
        for (int j = 0; j < 2; ++j) {   // B: 16 instrs, 2 per wave
            int rb = 32 * w + 16 * j;
            gload_lds16(Bk + (size_t)(rb + srow) * K + scg, &Bs[slot][rb * 32]);
        }
    };

    f32x4 acc[4][4];
#pragma unroll
    for (int i = 0; i < 4; ++i)
#pragma unroll
        for (int j = 0; j < 4; ++j)
            acc[i][j] = (f32x4){0.f, 0.f, 0.f, 0.f};

    const int NT = K / 32;
    stage(0, 0);
    stage(1, 1);

    int slot = 0, slot2 = 2;           // slot = t%3, slot2 = (t+2)%3
    for (int t = 0; t < NT; ++t) {
        asm volatile("s_waitcnt vmcnt(3)" ::: "memory");
        __builtin_amdgcn_s_barrier();
        __builtin_amdgcn_sched_barrier(0);
        __builtin_amdgcn_s_setprio(1);

        bf16x8 af[4], bf[4];
#pragma unroll
        for (int i = 0; i < 4; ++i) {
            int arow = wm * 64 + i * 16 + c16;
            af[i] = *(const bf16x8*)&As[slot][arow * 32 + rdc];
            int brow = wn * 64 + i * 16 + c16;
            bf[i] = *(const bf16x8*)&Bs[slot][brow * 32 + rdc];
        }
        int nk = t + 2;
        if (nk >= NT) nk -= NT;        // wrap-stage: keeps ledger uniform, never read
        stage(slot2, nk);

        // NO lgkmcnt(0) fence: compiler interleaves ds_reads with MFMAs (counted lgkmcnt)
#pragma unroll
        for (int i = 0; i < 4; ++i)
#pragma unroll
            for (int j = 0; j < 4; ++j)
                acc[i][j] = __builtin_amdgcn_mfma_f32_16x16x32_bf16(af[i], bf[j], acc[i][j], 0, 0, 0);
        __builtin_amdgcn_s_setprio(0);

        slot = (slot + 1) % 3;
        slot2 = (slot2 + 1) % 3;
    }

#pragma unroll
    for (int mi = 0; mi < 4; ++mi)
#pragma unroll
        for (int ni = 0; ni < 4; ++ni) {
            int col = bn * 256 + wn * 64 + ni * 16 + c16;
#pragma unroll
            for (int r = 0; r < 4; ++r) {
                int row = bm * 128 + wm * 64 + mi * 16 + g * 4 + r;
                C[(size_t)row * N + col] = (OutT)acc[mi][ni][r];
            }
        }
}

// ---------------- RoPE: in bf16 [S][ld] (head block at col h*128) -> out bf16 [H][S][128] ----------------
__global__ void rope_kernel(const bf16_t* __restrict__ in, bf16_t* __restrict__ out,
                            const int* __restrict__ pos, int H, int ld, float scale) {
    int idx = blockIdx.x * blockDim.x + threadIdx.x;
    int total = S_LEN * H * 64;
    if (idx >= total) return;
    int d = idx & 63;
    int h = (idx >> 6) % H;
    int s = idx / (64 * H);
    const bf16_t* base = in + (size_t)s * ld + h * HD;
    float x0 = (float)base[d], x1 = (float)base[d + 64];
    float p = (float)pos[s];
    float invf = fast_exp2(-0.20762050593046935f * (float)d);  // log2(10000)/64
    float f = p * invf;
    float sn, cs;
    __sincosf(f, &sn, &cs);
    float o0 = (x0 * cs - x1 * sn) * scale;
    float o1 = (x1 * cs + x0 * sn) * scale;
    bf16_t* ob = out + ((size_t)h * S_LEN + s) * HD;
    ob[d] = (bf16_t)o0;
    ob[d + 64] = (bf16_t)o1;
}

// ---------------- flash attention v3: 32 q-rows per wave ----------------
// Block = 4 waves x 32 rows = 128 q-rows. Each K/V fragment read from LDS feeds TWO
// row-groups' MFMAs -> LDS read traffic per FLOP halves (the round-11 bottleneck).
// Grid 512 (h = bid&31 fastest; segment s = bid>>5 -> x = s<8 ? s : 23-s so same-CU
// block pairs (b, b+256) have constant total work 34 tile-rounds). P buffer: 16 rows/wave,
// reused sequentially by the two row groups (in-wave LDS ordering, no barrier).
// ones-MFMA row-sum + defer-max THR=8 (exp2 domain) retained. LDS 74.2KB -> 2 blocks/CU.
#define PLD 68
__global__ __launch_bounds__(256) void attn_kernel(const bf16_t* __restrict__ Q,
                                                   const bf16_t* __restrict__ K,
                                                   const bf16_t* __restrict__ Vt,
                                                   bf16_t* __restrict__ O) {
    __shared__ bf16_t Ks[2][64 * 128];   // [kv row][d], swizzled chunks
    __shared__ bf16_t Vs[2][128 * 64];   // [d][kv], swizzled chunks
    __shared__ bf16_t Pl[4][16 * PLD];
    const int tid = threadIdx.x;
    const int lane = tid & 63, w = tid >> 6;
    const int bid = blockIdx.x;
    const int h = bid & 31;
    const int s = bid >> 5;              // 0..15
    const int x = (s < 8) ? s : 23 - s;  // balanced pairing: x(s)+x(s+8)=15
    const int kv = h >> 2;               // N_REP = 4
    const int qb = x * 128 + w * 32;     // wave's 32 q rows
    const int g = lane >> 4, c16 = lane & 15;
    const int c7 = c16 & 7;
    const bf16_t* Qh = Q + (size_t)h * S_LEN * HD;
    const bf16_t* Kh = K + (size_t)kv * S_LEN * HD;
    const bf16_t* Vh = Vt + (size_t)kv * HD * S_LEN;
    bf16_t* P = Pl[w];

    auto stage = [&](int buf, int kb) {
        bf16_t* Kd = Ks[buf];
        bf16_t* Vd = Vs[buf];
#pragma unroll
        for (int j = 0; j < 4; ++j) {
            int i = w * 4 + j;
            {   // K: instr covers 4 rows of 256B; lane l -> row 4i+(l>>4), chunk l&15
                int row = 4 * i + (lane >> 4);
                int sc = (lane & 15) ^ (row & 7);
                gload_lds16(Kh + (size_t)(kb + row) * HD + sc * 8, Kd + i * 512);
            }
            {   // V: instr covers 8 rows of 128B; lane l -> row 8i+(l>>3), chunk l&7
                int row = 8 * i + (lane >> 3);
                int sc = (lane & 7) ^ ((lane >> 3) & 7);
                gload_lds16(Vh + (size_t)row * S_LEN + kb + sc * 8, Vd + i * 512);
            }
        }
    };

    bf16x8 qf[2][4];
#pragma unroll
    for (int rg = 0; rg < 2; ++rg)
#pragma unroll
        for (int c = 0; c < 4; ++c)
            qf[rg][c] = *(const bf16x8*)(Qh + (size_t)(qb + rg * 16 + c16) * HD + c * 32 + g * 8);

    bf16x8 ones;
#pragma unroll
    for (int j = 0; j < 8; ++j) ones[j] = (bf16_t)1.0f;

    f32x4 acc_o[2][8];
#pragma unroll
    for (int rg = 0; rg < 2; ++rg)
#pragma unroll
        for (int dt = 0; dt < 8; ++dt) acc_o[rg][dt] = (f32x4){0.f, 0.f, 0.f, 0.f};
    f32x4 acc_l[2] = {(f32x4){0.f, 0.f, 0.f, 0.f}, (f32x4){0.f, 0.f, 0.f, 0.f}};
    float m[2][4];
#pragma unroll
    for (int rg = 0; rg < 2; ++rg)
#pragma unroll
        for (int r = 0; r < 4; ++r) m[rg][r] = -1e30f;

    const int nkt = 2 * x + 2;           // KVBLK=64
    stage(0, 0);
    __syncthreads();
    int cur = 0;

    bf16x8 pf[2][2];
    for (int kt = 0; kt < nkt; ++kt) {
        if (kt + 1 < nkt) stage(cur ^ 1, (kt + 1) * 64);
        const int kb = kt * 64;
        const bf16_t* Kb = Ks[cur];
        const bf16_t* Vb = Vs[cur];

        if (kb <= qb + 31) {             // wave-active (final tile masks out waves 0,1)
            const bool diag = (kb + 63 > qb);

            // joint QK^T: each kf read feeds BOTH row groups
            f32x4 sacc[2][4];
#pragma unroll
            for (int rg = 0; rg < 2; ++rg)
#pragma unroll
                for (int t = 0; t < 4; ++t) sacc[rg][t] = (f32x4){0.f, 0.f, 0.f, 0.f};
#pragma unroll
            for (int t = 0; t < 4; ++t) {
                const bf16_t* krow = Kb + (t * 16 + c16) * 128;
#pragma unroll
                for (int cc = 0; cc < 4; ++cc) {
                    bf16x8 kf = *(const bf16x8*)(krow + (((cc * 4 + g) ^ c7) * 8));
                    sacc[0][t] = __builtin_amdgcn_mfma_f32_16x16x32_bf16(qf[0][cc], kf, sacc[0][t], 0, 0, 0);
                    sacc[1][t] = __builtin_amdgcn_mfma_f32_16x16x32_bf16(qf[1][cc], kf, sacc[1][t], 0, 0, 0);
                }
            }
            // per row-group softmax; P buffer reused sequentially (in-wave ordering)
#pragma unroll
            for (int rg = 0; rg < 2; ++rg) {
                float p[4][4], mxr[4];
#pragma unroll
                for (int r = 0; r < 4; ++r) {
                    int qq = qb + rg * 16 + g * 4 + r;
#pragma unroll
                    for (int t = 0; t < 4; ++t) {
                        float sv = sacc[rg][t][r];
                        if (diag && (kb + t * 16 + c16 > qq)) sv = -1e30f;
                        p[t][r] = sv;
                    }
                    float mx = fmaxf(fmaxf(p[0][r], p[1][r]), fmaxf(p[2][r], p[3][r]));
                    mx = fmaxf(mx, __shfl_xor(mx, 1));
                    mx = fmaxf(mx, __shfl_xor(mx, 2));
                    mx = fmaxf(mx, __shfl_xor(mx, 4));
                    mx = fmaxf(mx, __shfl_xor(mx, 8));
                    mxr[r] = mx;
                }
                bool resc = false;
#pragma unroll
                for (int r = 0; r < 4; ++r) resc = resc || (mxr[r] > m[rg][r] + 8.f);
                if (__any(resc)) {
#pragma unroll
                    for (int r = 0; r < 4; ++r) {
                        float mn = fmaxf(m[rg][r], mxr[r]);
                        float al = fast_exp2(m[rg][r] - mn);
                        m[rg][r] = mn;
                        acc_l[rg][r] *= al;
#pragma unroll
                        for (int dt = 0; dt < 8; ++dt) acc_o[rg][dt][r] *= al;
                    }
                }
#pragma unroll
                for (int r = 0; r < 4; ++r)
#pragma unroll
                    for (int t = 0; t < 4; ++t)
                        p[t][r] = fast_exp2(p[t][r] - m[rg][r]);
#pragma unroll
                for (int t = 0; t < 4; ++t)
#pragma unroll
                    for (int r = 0; r < 4; ++r)
                        P[(g * 4 + r) * PLD + t * 16 + c16] = (bf16_t)p[t][r];
                pf[rg][0] = *(const bf16x8*)(P + c16 * PLD + g * 8);
                pf[rg][1] = *(const bf16x8*)(P + c16 * PLD + 32 + g * 8);
            }
            // row-sums on matrix pipe
            acc_l[0] = __builtin_amdgcn_mfma_f32_16x16x32_bf16(pf[0][0], ones, acc_l[0], 0, 0, 0);
            acc_l[0] = __builtin_amdgcn_mfma_f32_16x16x32_bf16(pf[0][1], ones, acc_l[0], 0, 0, 0);
            acc_l[1] = __builtin_amdgcn_mfma_f32_16x16x32_bf16(pf[1][0], ones, acc_l[1], 0, 0, 0);
            acc_l[1] = __builtin_amdgcn_mfma_f32_16x16x32_bf16(pf[1][1], ones, acc_l[1], 0, 0, 0);
            // PV: each vf read feeds BOTH row groups
#pragma unroll
            for (int dt = 0; dt < 8; ++dt) {
                const bf16_t* vrow = Vb + (dt * 16 + c16) * 64;
                bf16x8 vf0 = *(const bf16x8*)(vrow + ((g ^ c7) * 8));
                bf16x8 vf1 = *(const bf16x8*)(vrow + (((4 + g) ^ c7) * 8));
                acc_o[0][dt] = __builtin_amdgcn_mfma_f32_16x16x32_bf16(pf[0][0], vf0, acc_o[0][dt], 0, 0, 0);
                acc_o[0][dt] = __builtin_amdgcn_mfma_f32_16x16x32_bf16(pf[0][1], vf1, acc_o[0][dt], 0, 0, 0);
                acc_o[1][dt] = __builtin_amdgcn_mfma_f32_16x16x32_bf16(pf[1][0], vf0, acc_o[1][dt], 0, 0, 0);
                acc_o[1][dt] = __builtin_amdgcn_mfma_f32_16x16x32_bf16(pf[1][1], vf1, acc_o[1][dt], 0, 0, 0);
            }
        }
        __syncthreads();
        cur ^= 1;
    }
#pragma unroll
    for (int rg = 0; rg < 2; ++rg) {
        float inv_l[4];
#pragma unroll
        for (int r = 0; r < 4; ++r) inv_l[r] = 1.f / acc_l[rg][r];
#pragma unroll
        for (int dt = 0; dt < 8; ++dt)
#pragma unroll
            for (int r = 0; r < 4; ++r)
                O[(size_t)(qb + rg * 16 + g * 4 + r) * HIDDEN + h * HD + dt * 16 + c16] =
                    (bf16_t)(acc_o[rg][dt][r] * inv_l[r]);
    }
}

// ---------------- host ----------------
extern "C" void kernel_launch(void* const* d_in, const int* in_sizes, int n_in,
                              void* d_out, int out_size, void* d_ws, size_t ws_size,
                              hipStream_t stream) {
    const float* hs = (const float*)d_in[0];
    const float* Wq = (const float*)d_in[1];
    const float* Wk = (const float*)d_in[2];
    const float* Wv = (const float*)d_in[3];
    const float* Wo = (const float*)d_in[4];
    const int* pos = (const int*)d_in[6];
    float* out = (float*)d_out;

    char* ws = (char*)d_ws;
    size_t off = 0;
    auto alloc = [&](size_t bytes) -> void* {
        void* p = ws + off;
        off += (bytes + 255) & ~(size_t)255;
        return p;
    };
    bf16_t* hB    = (bf16_t*)alloc((size_t)S_LEN * HIDDEN * 2);
    bf16_t* WqkvT = (bf16_t*)alloc((size_t)NQKV * HIDDEN * 2);   // [6144][4096]
    bf16_t* WoT   = (bf16_t*)alloc((size_t)HIDDEN * HIDDEN * 2);
    bf16_t* QKV   = (bf16_t*)alloc((size_t)S_LEN * NQKV * 2);    // [2048][6144] bf16
    bf16_t* Qr    = (bf16_t*)alloc((size_t)NH * S_LEN * HD * 2);
    bf16_t* Kr    = (bf16_t*)alloc((size_t)NKV * S_LEN * HD * 2);
    bf16_t* Vt    = (bf16_t*)alloc((size_t)NKV * HD * S_LEN * 2);
    bf16_t* Oat   = (bf16_t*)alloc((size_t)S_LEN * HIDDEN * 2);

    dim3 tb(32, 8);
    // 1. cast hidden to bf16
    cast_bf16_kernel<<<2048, 256, 0, stream>>>(hs, hB, S_LEN * HIDDEN / 4);
    // 2. transpose-cast weights into fused [6144][4096]
    transpose_cast_kernel<<<dim3(HIDDEN / 32, HIDDEN / 32), tb, 0, stream>>>(Wq, WqkvT, HIDDEN, HIDDEN);
    transpose_cast_kernel<<<dim3(1024 / 32, HIDDEN / 32), tb, 0, stream>>>(Wk, WqkvT + (size_t)4096 * HIDDEN, 1024, HIDDEN);
    transpose_cast_kernel<<<dim3(1024 / 32, HIDDEN / 32), tb, 0, stream>>>(Wv, WqkvT + (size_t)5120 * HIDDEN, 1024, HIDDEN);
    transpose_cast_kernel<<<dim3(HIDDEN / 32, HIDDEN / 32), tb, 0, stream>>>(Wo, WoT, HIDDEN, HIDDEN);
    // 3. fused QKV projection -> bf16 [2048][6144], 384 blocks (full chip)
    gemm_ring_kernel<bf16_t><<<(S_LEN / 128) * (NQKV / 256), 512, 0, stream>>>(hB, WqkvT, QKV, S_LEN, NQKV, HIDDEN);
    // 4. RoPE; Q scale = log2(e)/sqrt(128) for exp2-domain softmax
    rope_kernel<<<(S_LEN * NH * 64 + 255) / 256, 256, 0, stream>>>(QKV, Qr, pos, NH, NQKV, 0.1275174310f);
    rope_kernel<<<(S_LEN * NKV * 64 + 255) / 256, 256, 0, stream>>>(QKV + 4096, Kr, pos, NKV, NQKV, 1.0f);
    // 5. V transpose: bf16 [S][1024] (stride 6144) -> [1024][2048] == [NKV][128][S]
    transpose_bf16_kernel<<<dim3(1024 / 32, S_LEN / 32), tb, 0, stream>>>(QKV + 5120, Vt, NQKV, S_LEN);
    // 6. flash attention (512 blocks: 16 segments x 32 heads, balanced pairing)
    attn_kernel<<<512, 256, 0, stream>>>(Qr, Kr, Vt, Oat);
    // 7. output projection (fp32 out), 256 blocks
    gemm_ring_kernel<float><<<(S_LEN / 128) * (HIDDEN / 256), 512, 0, stream>>>(Oat, WoT, out, S_LEN, HIDDEN, HIDDEN);
}

// Round 13
// 374.760 us; speedup vs baseline: 1.1752x; 1.0164x over previous
//
#include <hip/hip_runtime.h>
#include <hip/hip_bf16.h>

#define S_LEN 2048
#define HIDDEN 4096
#define NH 32
#define NKV 8
#define HD 128
#define NQKV 6144   // NH*HD + 2*NKV*HD

typedef __bf16 bf16_t;
typedef __bf16 bf16x8 __attribute__((ext_vector_type(8)));
typedef __bf16 bf16x4 __attribute__((ext_vector_type(4)));
typedef float f32x4 __attribute__((ext_vector_type(4)));

typedef __attribute__((address_space(1))) void gvoid;
typedef __attribute__((address_space(3))) void lvoid;

__device__ __forceinline__ void gload_lds16(const void* g, void* l) {
    __builtin_amdgcn_global_load_lds((gvoid*)g, (lvoid*)l, 16, 0, 0);
}

__device__ __forceinline__ float fast_exp2(float x) {
    return __builtin_amdgcn_exp2f(x);   // v_exp_f32 (2^x native)
}

// ---------------- cast fp32 -> bf16 (vectorized) ----------------
__global__ void cast_bf16_kernel(const float* __restrict__ in, bf16_t* __restrict__ out, int n4) {
    int stride = gridDim.x * blockDim.x;
    for (int idx = blockIdx.x * blockDim.x + threadIdx.x; idx < n4; idx += stride) {
        float4 v = ((const float4*)in)[idx];
        bf16x4 o;
        o.x = (bf16_t)v.x; o.y = (bf16_t)v.y; o.z = (bf16_t)v.z; o.w = (bf16_t)v.w;
        ((bf16x4*)out)[idx] = o;
    }
}

// ---------------- transpose + cast: in[R][C] fp32 (stride ldin) -> out[C][R] bf16 (stride ldout) ----------------
__global__ __launch_bounds__(256) void transpose_cast_kernel(const float* __restrict__ in,
                                                             bf16_t* __restrict__ out,
                                                             int ldin, int ldout) {
    __shared__ float t[32][33];
    int c0 = blockIdx.x * 32, r0 = blockIdx.y * 32;
    int tx = threadIdx.x, ty = threadIdx.y;
#pragma unroll
    for (int i = 0; i < 4; ++i)
        t[ty + i * 8][tx] = in[(size_t)(r0 + ty + i * 8) * ldin + c0 + tx];
    __syncthreads();
#pragma unroll
    for (int i = 0; i < 4; ++i)
        out[(size_t)(c0 + ty + i * 8) * ldout + r0 + tx] = (bf16_t)t[tx][ty + i * 8];
}

// ---------------- transpose bf16 -> bf16: in[R][C] (stride ldin) -> out[C][R] (stride ldout) ----------------
__global__ __launch_bounds__(256) void transpose_bf16_kernel(const bf16_t* __restrict__ in,
                                                             bf16_t* __restrict__ out,
                                                             int ldin, int ldout) {
    __shared__ float t[32][33];
    int c0 = blockIdx.x * 32, r0 = blockIdx.y * 32;
    int tx = threadIdx.x, ty = threadIdx.y;
#pragma unroll
    for (int i = 0; i < 4; ++i)
        t[ty + i * 8][tx] = (float)in[(size_t)(r0 + ty + i * 8) * ldin + c0 + tx];
    __syncthreads();
#pragma unroll
    for (int i = 0; i < 4; ++i)
        out[(size_t)(c0 + ty + i * 8) * ldout + r0 + tx] = (bf16_t)t[tx][ty + i * 8];
}

// ---------------- ring-3 counted-vmcnt GEMM: C[M][N] = A[M][K] @ Bt[N][K]^T ----------------
// (unchanged — best measured GEMM structure)
template<typename OutT>
__global__ __launch_bounds__(512, 2) void gemm_ring_kernel(const bf16_t* __restrict__ A,
                                                           const bf16_t* __restrict__ Bt,
                                                           OutT* __restrict__ C,
                                                           int M, int N, int K) {
    __shared__ bf16_t As[3][128 * 32];
    __shared__ bf16_t Bs[3][256 * 32];
    const int tid = threadIdx.x;
    const int lane = tid & 63, w = tid >> 6;
    const int wm = w >> 2, wn = w & 3;
    const int g = lane >> 4, c16 = lane & 15;
    const int srow = lane >> 2;                              // row within a 16-row DMA instr
    const int scg = ((lane & 3) ^ ((lane >> 3) & 3)) * 8;    // pre-swizzled global chunk (elems)
    const int rdc = (g ^ ((c16 >> 1) & 3)) * 8;              // swizzled read chunk (elems)

    // XCD swizzle, bm-fastest
    const int nbm = M / 128;
    const int cpx = gridDim.x >> 3;
    const int bid = blockIdx.x;
    const int swz = (bid & 7) * cpx + (bid >> 3);
    const int bm = swz % nbm, bn = swz / nbm;

    const bf16_t* Ab = A + (size_t)(bm * 128) * K;
    const bf16_t* Bb = Bt + (size_t)(bn * 256) * K;

    auto stage = [&](int slot, int kt) {
        const bf16_t* Ak = Ab + (size_t)kt * 32;
        const bf16_t* Bk = Bb + (size_t)kt * 32;
        {   // A: 8 instrs total, 1 per wave: rows 16w..16w+15
            int rb = 16 * w;
            gload_lds16(Ak + (size_t)(rb + srow) * K + scg, &As[slot][rb * 32]);
        }
#pragma unroll
        for (int j = 0; j < 2; ++j) {   // B: 16 instrs, 2 per wave
            int rb = 32 * w + 16 * j;
            gload_lds16(Bk + (size_t)(rb + srow) * K + scg, &Bs[slot][rb * 32]);
        }
    };

    f32x4 acc[4][4];
#pragma unroll
    for (int i = 0; i < 4; ++i)
#pragma unroll
        for (int j = 0; j < 4; ++j)
            acc[i][j] = (f32x4){0.f, 0.f, 0.f, 0.f};

    const int NT = K / 32;
    stage(0, 0);
    stage(1, 1);

    int slot = 0, slot2 = 2;           // slot = t%3, slot2 = (t+2)%3
    for (int t = 0; t < NT; ++t) {
        asm volatile("s_waitcnt vmcnt(3)" ::: "memory");
        __builtin_amdgcn_s_barrier();
        __builtin_amdgcn_sched_barrier(0);
        __builtin_amdgcn_s_setprio(1);

        bf16x8 af[4], bf[4];
#pragma unroll
        for (int i = 0; i < 4; ++i) {
            int arow = wm * 64 + i * 16 + c16;
            af[i] = *(const bf16x8*)&As[slot][arow * 32 + rdc];
            int brow = wn * 64 + i * 16 + c16;
            bf[i] = *(const bf16x8*)&Bs[slot][brow * 32 + rdc];
        }
        int nk = t + 2;
        if (nk >= NT) nk -= NT;        // wrap-stage: keeps ledger uniform, never read
        stage(slot2, nk);

        // NO lgkmcnt(0) fence: compiler interleaves ds_reads with MFMAs (counted lgkmcnt)
#pragma unroll
        for (int i = 0; i < 4; ++i)
#pragma unroll
            for (int j = 0; j < 4; ++j)
                acc[i][j] = __builtin_amdgcn_mfma_f32_16x16x32_bf16(af[i], bf[j], acc[i][j], 0, 0, 0);
        __builtin_amdgcn_s_setprio(0);

        slot = (slot + 1) % 3;
        slot2 = (slot2 + 1) % 3;
    }

#pragma unroll
    for (int mi = 0; mi < 4; ++mi)
#pragma unroll
        for (int ni = 0; ni < 4; ++ni) {
            int col = bn * 256 + wn * 64 + ni * 16 + c16;
#pragma unroll
            for (int r = 0; r < 4; ++r) {
                int row = bm * 128 + wm * 64 + mi * 16 + g * 4 + r;
                C[(size_t)row * N + col] = (OutT)acc[mi][ni][r];
            }
        }
}

// ---------------- RoPE: in bf16 [S][ld] (head block at col h*128) -> out bf16 [H][S][128] ----------------
__global__ void rope_kernel(const bf16_t* __restrict__ in, bf16_t* __restrict__ out,
                            const int* __restrict__ pos, int H, int ld, float scale) {
    int idx = blockIdx.x * blockDim.x + threadIdx.x;
    int total = S_LEN * H * 64;
    if (idx >= total) return;
    int d = idx & 63;
    int h = (idx >> 6) % H;
    int s = idx / (64 * H);
    const bf16_t* base = in + (size_t)s * ld + h * HD;
    float x0 = (float)base[d], x1 = (float)base[d + 64];
    float p = (float)pos[s];
    float invf = fast_exp2(-0.20762050593046935f * (float)d);  // log2(10000)/64
    float f = p * invf;
    float sn, cs;
    __sincosf(f, &sn, &cs);
    float o0 = (x0 * cs - x1 * sn) * scale;
    float o1 = (x1 * cs + x0 * sn) * scale;
    bf16_t* ob = out + ((size_t)h * S_LEN + s) * HD;
    ob[d] = (bf16_t)o0;
    ob[d + 64] = (bf16_t)o1;
}

// ---------------- flash attention v4: mirrored-pair blocks, 1 block/CU ----------------
// Grid 256 = 8 x-values x 32 heads, 512 threads (8 waves). Block owns q-tiles {x, 15-x}
// (128 rows each): waves 0-3 -> tile x, waves 4-7 -> tile 15-x, each wave 32 q-rows.
// One shared K/V stream of nkt = 32-2x tiles serves both tiles (wave-active check skips
// compute once kb passes a wave's rows). Per-CU work deterministic (1 block/CU, all
// resident at t=0) -> no scheduler-pairing luck, no dispatch tail (the round-12 diagnosis:
// occupancy 11% = CUs idle from unlucky block placement, not any pipe limit).
// LDS: K dbuf 32K + V dbuf 32K + P 8x2176 = 83 KB -> 1 block/CU.
#define PLD 68
__global__ __launch_bounds__(512) void attn_kernel(const bf16_t* __restrict__ Q,
                                                   const bf16_t* __restrict__ K,
                                                   const bf16_t* __restrict__ Vt,
                                                   bf16_t* __restrict__ O) {
    __shared__ bf16_t Ks[2][64 * 128];   // [kv row][d], swizzled chunks
    __shared__ bf16_t Vs[2][128 * 64];   // [d][kv], swizzled chunks
    __shared__ bf16_t Pl[8][16 * PLD];
    const int tid = threadIdx.x;
    const int lane = tid & 63, w = tid >> 6;   // w: 0..7
    const int bid = blockIdx.x;
    const int h = bid & 31;
    const int x = bid >> 5;              // 0..7
    const int wg = w >> 2, wi = w & 3;
    const int qtile = wg == 0 ? x : 15 - x;
    const int qb = qtile * 128 + wi * 32;      // wave's 32 q rows
    const int kv = h >> 2;               // N_REP = 4
    const int g = lane >> 4, c16 = lane & 15;
    const int c7 = c16 & 7;
    const bf16_t* Qh = Q + (size_t)h * S_LEN * HD;
    const bf16_t* Kh = K + (size_t)kv * S_LEN * HD;
    const bf16_t* Vh = Vt + (size_t)kv * HD * S_LEN;
    bf16_t* P = Pl[w];

    auto stage = [&](int buf, int kb) {
        bf16_t* Kd = Ks[buf];
        bf16_t* Vd = Vs[buf];
#pragma unroll
        for (int j = 0; j < 2; ++j) {
            int i = w * 2 + j;           // 16 instrs across 8 waves
            {   // K: instr covers 4 rows of 256B; lane l -> row 4i+(l>>4), chunk l&15
                int row = 4 * i + (lane >> 4);
                int sc = (lane & 15) ^ (row & 7);
                gload_lds16(Kh + (size_t)(kb + row) * HD + sc * 8, Kd + i * 512);
            }
            {   // V: instr covers 8 rows of 128B; lane l -> row 8i+(l>>3), chunk l&7
                int row = 8 * i + (lane >> 3);
                int sc = (lane & 7) ^ ((lane >> 3) & 7);
                gload_lds16(Vh + (size_t)row * S_LEN + kb + sc * 8, Vd + i * 512);
            }
        }
    };

    bf16x8 qf[2][4];
#pragma unroll
    for (int rg = 0; rg < 2; ++rg)
#pragma unroll
        for (int c = 0; c < 4; ++c)
            qf[rg][c] = *(const bf16x8*)(Qh + (size_t)(qb + rg * 16 + c16) * HD + c * 32 + g * 8);

    bf16x8 ones;
#pragma unroll
    for (int j = 0; j < 8; ++j) ones[j] = (bf16_t)1.0f;

    f32x4 acc_o[2][8];
#pragma unroll
    for (int rg = 0; rg < 2; ++rg)
#pragma unroll
        for (int dt = 0; dt < 8; ++dt) acc_o[rg][dt] = (f32x4){0.f, 0.f, 0.f, 0.f};
    f32x4 acc_l[2] = {(f32x4){0.f, 0.f, 0.f, 0.f}, (f32x4){0.f, 0.f, 0.f, 0.f}};
    float m[2][4];
#pragma unroll
    for (int rg = 0; rg < 2; ++rg)
#pragma unroll
        for (int r = 0; r < 4; ++r) m[rg][r] = -1e30f;

    const int nkt = 32 - 2 * x;          // covers tile 15-x (32-2x) and tile x (2x+2 <= 16)
    stage(0, 0);
    __syncthreads();
    int cur = 0;

    bf16x8 pf[2][2];
    for (int kt = 0; kt < nkt; ++kt) {
        if (kt + 1 < nkt) stage(cur ^ 1, (kt + 1) * 64);
        const int kb = kt * 64;
        const bf16_t* Kb = Ks[cur];
        const bf16_t* Vb = Vs[cur];

        if (kb <= qb + 31) {             // wave-active
            const bool diag = (kb + 63 > qb);

            // joint QK^T: each kf read feeds BOTH row groups
            f32x4 sacc[2][4];
#pragma unroll
            for (int rg = 0; rg < 2; ++rg)
#pragma unroll
                for (int t = 0; t < 4; ++t) sacc[rg][t] = (f32x4){0.f, 0.f, 0.f, 0.f};
#pragma unroll
            for (int t = 0; t < 4; ++t) {
                const bf16_t* krow = Kb + (t * 16 + c16) * 128;
#pragma unroll
                for (int cc = 0; cc < 4; ++cc) {
                    bf16x8 kf = *(const bf16x8*)(krow + (((cc * 4 + g) ^ c7) * 8));
                    sacc[0][t] = __builtin_amdgcn_mfma_f32_16x16x32_bf16(qf[0][cc], kf, sacc[0][t], 0, 0, 0);
                    sacc[1][t] = __builtin_amdgcn_mfma_f32_16x16x32_bf16(qf[1][cc], kf, sacc[1][t], 0, 0, 0);
                }
            }
            // per row-group softmax; P buffer reused sequentially (in-wave ordering)
#pragma unroll
            for (int rg = 0; rg < 2; ++rg) {
                float p[4][4], mxr[4];
#pragma unroll
                for (int r = 0; r < 4; ++r) {
                    int qq = qb + rg * 16 + g * 4 + r;
#pragma unroll
                    for (int t = 0; t < 4; ++t) {
                        float sv = sacc[rg][t][r];
                        if (diag && (kb + t * 16 + c16 > qq)) sv = -1e30f;
                        p[t][r] = sv;
                    }
                    float mx = fmaxf(fmaxf(p[0][r], p[1][r]), fmaxf(p[2][r], p[3][r]));
                    mx = fmaxf(mx, __shfl_xor(mx, 1));
                    mx = fmaxf(mx, __shfl_xor(mx, 2));
                    mx = fmaxf(mx, __shfl_xor(mx, 4));
                    mx = fmaxf(mx, __shfl_xor(mx, 8));
                    mxr[r] = mx;
                }
                bool resc = false;
#pragma unroll
                for (int r = 0; r < 4; ++r) resc = resc || (mxr[r] > m[rg][r] + 8.f);
                if (__any(resc)) {
#pragma unroll
                    for (int r = 0; r < 4; ++r) {
                        float mn = fmaxf(m[rg][r], mxr[r]);
                        float al = fast_exp2(m[rg][r] - mn);
                        m[rg][r] = mn;
                        acc_l[rg][r] *= al;
#pragma unroll
                        for (int dt = 0; dt < 8; ++dt) acc_o[rg][dt][r] *= al;
                    }
                }
#pragma unroll
                for (int r = 0; r < 4; ++r)
#pragma unroll
                    for (int t = 0; t < 4; ++t)
                        p[t][r] = fast_exp2(p[t][r] - m[rg][r]);
#pragma unroll
                for (int t = 0; t < 4; ++t)
#pragma unroll
                    for (int r = 0; r < 4; ++r)
                        P[(g * 4 + r) * PLD + t * 16 + c16] = (bf16_t)p[t][r];
                pf[rg][0] = *(const bf16x8*)(P + c16 * PLD + g * 8);
                pf[rg][1] = *(const bf16x8*)(P + c16 * PLD + 32 + g * 8);
            }
            // row-sums on matrix pipe
            acc_l[0] = __builtin_amdgcn_mfma_f32_16x16x32_bf16(pf[0][0], ones, acc_l[0], 0, 0, 0);
            acc_l[0] = __builtin_amdgcn_mfma_f32_16x16x32_bf16(pf[0][1], ones, acc_l[0], 0, 0, 0);
            acc_l[1] = __builtin_amdgcn_mfma_f32_16x16x32_bf16(pf[1][0], ones, acc_l[1], 0, 0, 0);
            acc_l[1] = __builtin_amdgcn_mfma_f32_16x16x32_bf16(pf[1][1], ones, acc_l[1], 0, 0, 0);
            // PV: each vf read feeds BOTH row groups
#pragma unroll
            for (int dt = 0; dt < 8; ++dt) {
                const bf16_t* vrow = Vb + (dt * 16 + c16) * 64;
                bf16x8 vf0 = *(const bf16x8*)(vrow + ((g ^ c7) * 8));
                bf16x8 vf1 = *(const bf16x8*)(vrow + (((4 + g) ^ c7) * 8));
                acc_o[0][dt] = __builtin_amdgcn_mfma_f32_16x16x32_bf16(pf[0][0], vf0, acc_o[0][dt], 0, 0, 0);
                acc_o[0][dt] = __builtin_amdgcn_mfma_f32_16x16x32_bf16(pf[0][1], vf1, acc_o[0][dt], 0, 0, 0);
                acc_o[1][dt] = __builtin_amdgcn_mfma_f32_16x16x32_bf16(pf[1][0], vf0, acc_o[1][dt], 0, 0, 0);
                acc_o[1][dt] = __builtin_amdgcn_mfma_f32_16x16x32_bf16(pf[1][1], vf1, acc_o[1][dt], 0, 0, 0);
            }
        }
        __syncthreads();
        cur ^= 1;
    }
#pragma unroll
    for (int rg = 0; rg < 2; ++rg) {
        float inv_l[4];
#pragma unroll
        for (int r = 0; r < 4; ++r) inv_l[r] = 1.f / acc_l[rg][r];
#pragma unroll
        for (int dt = 0; dt < 8; ++dt)
#pragma unroll
            for (int r = 0; r < 4; ++r)
                O[(size_t)(qb + rg * 16 + g * 4 + r) * HIDDEN + h * HD + dt * 16 + c16] =
                    (bf16_t)(acc_o[rg][dt][r] * inv_l[r]);
    }
}

// ---------------- host ----------------
extern "C" void kernel_launch(void* const* d_in, const int* in_sizes, int n_in,
                              void* d_out, int out_size, void* d_ws, size_t ws_size,
                              hipStream_t stream) {
    const float* hs = (const float*)d_in[0];
    const float* Wq = (const float*)d_in[1];
    const float* Wk = (const float*)d_in[2];
    const float* Wv = (const float*)d_in[3];
    const float* Wo = (const float*)d_in[4];
    const int* pos = (const int*)d_in[6];
    float* out = (float*)d_out;

    char* ws = (char*)d_ws;
    size_t off = 0;
    auto alloc = [&](size_t bytes) -> void* {
        void* p = ws + off;
        off += (bytes + 255) & ~(size_t)255;
        return p;
    };
    bf16_t* hB    = (bf16_t*)alloc((size_t)S_LEN * HIDDEN * 2);
    bf16_t* WqkvT = (bf16_t*)alloc((size_t)NQKV * HIDDEN * 2);   // [6144][4096]
    bf16_t* WoT   = (bf16_t*)alloc((size_t)HIDDEN * HIDDEN * 2);
    bf16_t* QKV   = (bf16_t*)alloc((size_t)S_LEN * NQKV * 2);    // [2048][6144] bf16
    bf16_t* Qr    = (bf16_t*)alloc((size_t)NH * S_LEN * HD * 2);
    bf16_t* Kr    = (bf16_t*)alloc((size_t)NKV * S_LEN * HD * 2);
    bf16_t* Vt    = (bf16_t*)alloc((size_t)NKV * HD * S_LEN * 2);
    bf16_t* Oat   = (bf16_t*)alloc((size_t)S_LEN * HIDDEN * 2);

    dim3 tb(32, 8);
    // 1. cast hidden to bf16
    cast_bf16_kernel<<<2048, 256, 0, stream>>>(hs, hB, S_LEN * HIDDEN / 4);
    // 2. transpose-cast weights into fused [6144][4096]
    transpose_cast_kernel<<<dim3(HIDDEN / 32, HIDDEN / 32), tb, 0, stream>>>(Wq, WqkvT, HIDDEN, HIDDEN);
    transpose_cast_kernel<<<dim3(1024 / 32, HIDDEN / 32), tb, 0, stream>>>(Wk, WqkvT + (size_t)4096 * HIDDEN, 1024, HIDDEN);
    transpose_cast_kernel<<<dim3(1024 / 32, HIDDEN / 32), tb, 0, stream>>>(Wv, WqkvT + (size_t)5120 * HIDDEN, 1024, HIDDEN);
    transpose_cast_kernel<<<dim3(HIDDEN / 32, HIDDEN / 32), tb, 0, stream>>>(Wo, WoT, HIDDEN, HIDDEN);
    // 3. fused QKV projection -> bf16 [2048][6144], 384 blocks (full chip)
    gemm_ring_kernel<bf16_t><<<(S_LEN / 128) * (NQKV / 256), 512, 0, stream>>>(hB, WqkvT, QKV, S_LEN, NQKV, HIDDEN);
    // 4. RoPE; Q scale = log2(e)/sqrt(128) for exp2-domain softmax
    rope_kernel<<<(S_LEN * NH * 64 + 255) / 256, 256, 0, stream>>>(QKV, Qr, pos, NH, NQKV, 0.1275174310f);
    rope_kernel<<<(S_LEN * NKV * 64 + 255) / 256, 256, 0, stream>>>(QKV + 4096, Kr, pos, NKV, NQKV, 1.0f);
    // 5. V transpose: bf16 [S][1024] (stride 6144) -> [1024][2048] == [NKV][128][S]
    transpose_bf16_kernel<<<dim3(1024 / 32, S_LEN / 32), tb, 0, stream>>>(QKV + 5120, Vt, NQKV, S_LEN);
    // 6. flash attention: 256 blocks (8 mirrored-pair segments x 32 heads), 1/CU
    attn_kernel<<<256, 512, 0, stream>>>(Qr, Kr, Vt, Oat);
    // 7. output projection (fp32 out), 256 blocks
    gemm_ring_kernel<float><<<(S_LEN / 128) * (HIDDEN / 256), 512, 0, stream>>>(Oat, WoT, out, S_LEN, HIDDEN, HIDDEN);
}

// Round 14
// 365.759 us; speedup vs baseline: 1.2041x; 1.0246x over previous
//
#include <hip/hip_runtime.h>
#include <hip/hip_bf16.h>

#define S_LEN 2048
#define HIDDEN 4096
#define NH 32
#define NKV 8
#define HD 128
#define NQKV 6144   // NH*HD + 2*NKV*HD

typedef __bf16 bf16_t;
typedef __bf16 bf16x8 __attribute__((ext_vector_type(8)));
typedef __bf16 bf16x4 __attribute__((ext_vector_type(4)));
typedef float f32x4 __attribute__((ext_vector_type(4)));

typedef __attribute__((address_space(1))) void gvoid;
typedef __attribute__((address_space(3))) void lvoid;

__device__ __forceinline__ void gload_lds16(const void* g, void* l) {
    __builtin_amdgcn_global_load_lds((gvoid*)g, (lvoid*)l, 16, 0, 0);
}

__device__ __forceinline__ float fast_exp2(float x) {
    return __builtin_amdgcn_exp2f(x);   // v_exp_f32 (2^x native)
}

__device__ __forceinline__ unsigned int pack2_bf16(float lo, float hi) {
    bf16_t l = (bf16_t)lo, h = (bf16_t)hi;
    unsigned short lu, hu;
    __builtin_memcpy(&lu, &l, 2);
    __builtin_memcpy(&hu, &h, 2);
    return ((unsigned int)hu << 16) | (unsigned int)lu;
}

// ---------------- cast fp32 -> bf16 (vectorized) ----------------
__global__ void cast_bf16_kernel(const float* __restrict__ in, bf16_t* __restrict__ out, int n4) {
    int stride = gridDim.x * blockDim.x;
    for (int idx = blockIdx.x * blockDim.x + threadIdx.x; idx < n4; idx += stride) {
        float4 v = ((const float4*)in)[idx];
        bf16x4 o;
        o.x = (bf16_t)v.x; o.y = (bf16_t)v.y; o.z = (bf16_t)v.z; o.w = (bf16_t)v.w;
        ((bf16x4*)out)[idx] = o;
    }
}

// ---------------- fast transpose+cast: fp32 in[R][C] (ldin) -> bf16 out[C][R] (ldout) ----------------
// 64x64 tile, 256 threads. Phase A: float4 loads of row pairs, pack (r,r+1) into u32,
// scatter to t2[col][rowpair] (pad 34 -> 4-way write conflict max). Phase B: contiguous
// u32-row reads (2-way) + 16B coalesced stores. grid (C/64, R/64).
__global__ __launch_bounds__(256) void transpose_cast_kernel(const float* __restrict__ in,
                                                             bf16_t* __restrict__ out,
                                                             int ldin, int ldout) {
    __shared__ unsigned int t2[64][34];
    const int c0 = blockIdx.x * 64, r0 = blockIdx.y * 64;
    const int t = threadIdx.x;
    const int tx4 = t & 15, tp = t >> 4;
#pragma unroll
    for (int i = 0; i < 2; ++i) {
        int rp = tp + i * 16;
        const float* p0 = &in[(size_t)(r0 + 2 * rp) * ldin + c0 + tx4 * 4];
        float4 a = *(const float4*)p0;
        float4 b = *(const float4*)(p0 + ldin);
        t2[tx4 * 4 + 0][rp] = pack2_bf16(a.x, b.x);
        t2[tx4 * 4 + 1][rp] = pack2_bf16(a.y, b.y);
        t2[tx4 * 4 + 2][rp] = pack2_bf16(a.z, b.z);
        t2[tx4 * 4 + 3][rp] = pack2_bf16(a.w, b.w);
    }
    __syncthreads();
    const int q = t & 3, cc = t >> 2;
    uint2 v0 = *(const uint2*)&t2[cc][q * 8 + 0];
    uint2 v1 = *(const uint2*)&t2[cc][q * 8 + 2];
    uint2 v2 = *(const uint2*)&t2[cc][q * 8 + 4];
    uint2 v3 = *(const uint2*)&t2[cc][q * 8 + 6];
    bf16_t* o = &out[(size_t)(c0 + cc) * ldout + r0 + q * 16];
    *(uint4*)o = make_uint4(v0.x, v0.y, v1.x, v1.y);
    *(uint4*)(o + 8) = make_uint4(v2.x, v2.y, v3.x, v3.y);
}

// ---------------- fast transpose bf16 -> bf16 (same scheme, bf16x4 loads) ----------------
__global__ __launch_bounds__(256) void transpose_bf16_kernel(const bf16_t* __restrict__ in,
                                                             bf16_t* __restrict__ out,
                                                             int ldin, int ldout) {
    __shared__ unsigned int t2[64][34];
    const int c0 = blockIdx.x * 64, r0 = blockIdx.y * 64;
    const int t = threadIdx.x;
    const int tx4 = t & 15, tp = t >> 4;
#pragma unroll
    for (int i = 0; i < 2; ++i) {
        int rp = tp + i * 16;
        const bf16_t* p0 = &in[(size_t)(r0 + 2 * rp) * ldin + c0 + tx4 * 4];
        bf16x4 a = *(const bf16x4*)p0;
        bf16x4 b = *(const bf16x4*)(p0 + ldin);
#pragma unroll
        for (int k2 = 0; k2 < 4; ++k2) {
            unsigned short lu, hu;
            bf16_t la = a[k2], hb = b[k2];
            __builtin_memcpy(&lu, &la, 2);
            __builtin_memcpy(&hu, &hb, 2);
            t2[tx4 * 4 + k2][rp] = ((unsigned int)hu << 16) | (unsigned int)lu;
        }
    }
    __syncthreads();
    const int q = t & 3, cc = t >> 2;
    uint2 v0 = *(const uint2*)&t2[cc][q * 8 + 0];
    uint2 v1 = *(const uint2*)&t2[cc][q * 8 + 2];
    uint2 v2 = *(const uint2*)&t2[cc][q * 8 + 4];
    uint2 v3 = *(const uint2*)&t2[cc][q * 8 + 6];
    bf16_t* o = &out[(size_t)(c0 + cc) * ldout + r0 + q * 16];
    *(uint4*)o = make_uint4(v0.x, v0.y, v1.x, v1.y);
    *(uint4*)(o + 8) = make_uint4(v2.x, v2.y, v3.x, v3.y);
}

// ---------------- ring-3 counted-vmcnt GEMM: C[M][N] = A[M][K] @ Bt[N][K]^T ----------------
// 128xBN tile (BN in {128,192,256}), BK=32/phase, 8 waves (2m x 4n), 512 threads.
// Ring-3 LDS; per phase: {vmcnt(VMN); barrier; ds_read frags (compiler-interleaved with
// MFMA via counted lgkmcnt); stage chunk t+2; MFMAs}. Per-wave stage loads: BN=256: 3
// (vmcnt 3 exact); BN=192: waves 0-3 B x3, waves 4-7 A x2 (vmcnt(2) exact-or-stricter);
// BN=128: A+B 1 each (vmcnt 2 exact). Grid sized to EXACTLY 2 blocks/CU for balance.
// Swizzle (rule #21): linear LDS dest; global chunk (l&3)^((l>>3)&3); read chunk g^((c16>>1)&3).
template<int BN, typename OutT>
__global__ __launch_bounds__(512, 2) void gemm_ring_kernel(const bf16_t* __restrict__ A,
                                                           const bf16_t* __restrict__ Bt,
                                                           OutT* __restrict__ C,
                                                           int M, int N, int K) {
    constexpr int NF = BN / 64;          // per-wave n frags
    constexpr int VMN = (BN == 256) ? 3 : 2;
    __shared__ bf16_t As[3][128 * 32];
    __shared__ bf16_t Bs[3][BN * 32];
    const int tid = threadIdx.x;
    const int lane = tid & 63, w = tid >> 6;
    const int wm = w >> 2, wn = w & 3;
    const int g = lane >> 4, c16 = lane & 15;
    const int srow = lane >> 2;
    const int scg = ((lane & 3) ^ ((lane >> 3) & 3)) * 8;
    const int rdc = (g ^ ((c16 >> 1) & 3)) * 8;

    // XCD swizzle, bm-fastest
    const int nbm = M / 128;
    const int cpx = gridDim.x >> 3;
    const int bid = blockIdx.x;
    const int swz = (bid & 7) * cpx + (bid >> 3);
    const int bm = swz % nbm, bn = swz / nbm;

    const bf16_t* Ab = A + (size_t)(bm * 128) * K;
    const bf16_t* Bb = Bt + (size_t)bn * BN * K;

    auto stage = [&](int slot, int kt) {
        const bf16_t* Ak = Ab + (size_t)kt * 32;
        const bf16_t* Bk = Bb + (size_t)kt * 32;
        if constexpr (BN == 256) {
            int rb = 16 * w;
            gload_lds16(Ak + (size_t)(rb + srow) * K + scg, &As[slot][rb * 32]);
#pragma unroll
            for (int j = 0; j < 2; ++j) {
                int rb2 = 32 * w + 16 * j;
                gload_lds16(Bk + (size_t)(rb2 + srow) * K + scg, &Bs[slot][rb2 * 32]);
            }
        } else if constexpr (BN == 192) {
            if (w < 4) {
#pragma unroll
                for (int j = 0; j < 3; ++j) {
                    int rb = 48 * w + 16 * j;
                    gload_lds16(Bk + (size_t)(rb + srow) * K + scg, &Bs[slot][rb * 32]);
                }
            } else {
#pragma unroll
                for (int j = 0; j < 2; ++j) {
                    int rb = 32 * (w - 4) + 16 * j;
                    gload_lds16(Ak + (size_t)(rb + srow) * K + scg, &As[slot][rb * 32]);
                }
            }
        } else {   // BN == 128
            int rb = 16 * w;
            gload_lds16(Ak + (size_t)(rb + srow) * K + scg, &As[slot][rb * 32]);
            gload_lds16(Bk + (size_t)(rb + srow) * K + scg, &Bs[slot][rb * 32]);
        }
    };

    f32x4 acc[4][NF];
#pragma unroll
    for (int i = 0; i < 4; ++i)
#pragma unroll
        for (int j = 0; j < NF; ++j)
            acc[i][j] = (f32x4){0.f, 0.f, 0.f, 0.f};

    const int NT = K / 32;
    stage(0, 0);
    stage(1, 1);

    int slot = 0, slot2 = 2;
    for (int t = 0; t < NT; ++t) {
        asm volatile("s_waitcnt vmcnt(%0)" :: "n"(VMN) : "memory");
        __builtin_amdgcn_s_barrier();
        __builtin_amdgcn_sched_barrier(0);
        __builtin_amdgcn_s_setprio(1);

        bf16x8 af[4], bf[NF];
#pragma unroll
        for (int i = 0; i < 4; ++i) {
            int arow = wm * 64 + i * 16 + c16;
            af[i] = *(const bf16x8*)&As[slot][arow * 32 + rdc];
        }
#pragma unroll
        for (int j = 0; j < NF; ++j) {
            int brow = wn * (BN / 4) + j * 16 + c16;
            bf[j] = *(const bf16x8*)&Bs[slot][brow * 32 + rdc];
        }
        int nk = t + 2;
        if (nk >= NT) nk -= NT;        // wrap-stage: keeps ledger uniform, never read
        stage(slot2, nk);

        // NO lgkmcnt(0) fence: compiler interleaves ds_reads with MFMAs (counted lgkmcnt)
#pragma unroll
        for (int i = 0; i < 4; ++i)
#pragma unroll
            for (int j = 0; j < NF; ++j)
                acc[i][j] = __builtin_amdgcn_mfma_f32_16x16x32_bf16(af[i], bf[j], acc[i][j], 0, 0, 0);
        __builtin_amdgcn_s_setprio(0);

        slot = (slot + 1) % 3;
        slot2 = (slot2 + 1) % 3;
    }

#pragma unroll
    for (int mi = 0; mi < 4; ++mi)
#pragma unroll
        for (int ni = 0; ni < NF; ++ni) {
            int col = bn * BN + wn * (BN / 4) + ni * 16 + c16;
#pragma unroll
            for (int r = 0; r < 4; ++r) {
                int row = bm * 128 + wm * 64 + mi * 16 + g * 4 + r;
                C[(size_t)row * N + col] = (OutT)acc[mi][ni][r];
            }
        }
}

// ---------------- RoPE: in bf16 [S][ld] (head block at col h*128) -> out bf16 [H][S][128] ----------------
__global__ void rope_kernel(const bf16_t* __restrict__ in, bf16_t* __restrict__ out,
                            const int* __restrict__ pos, int H, int ld, float scale) {
    int idx = blockIdx.x * blockDim.x + threadIdx.x;
    int total = S_LEN * H * 64;
    if (idx >= total) return;
    int d = idx & 63;
    int h = (idx >> 6) % H;
    int s = idx / (64 * H);
    const bf16_t* base = in + (size_t)s * ld + h * HD;
    float x0 = (float)base[d], x1 = (float)base[d + 64];
    float p = (float)pos[s];
    float invf = fast_exp2(-0.20762050593046935f * (float)d);  // log2(10000)/64
    float f = p * invf;
    float sn, cs;
    __sincosf(f, &sn, &cs);
    float o0 = (x0 * cs - x1 * sn) * scale;
    float o1 = (x1 * cs + x0 * sn) * scale;
    bf16_t* ob = out + ((size_t)h * S_LEN + s) * HD;
    ob[d] = (bf16_t)o0;
    ob[d + 64] = (bf16_t)o1;
}

// ---------------- flash attention v4: mirrored-pair blocks, 1 block/CU (unchanged) ----------------
#define PLD 68
__global__ __launch_bounds__(512) void attn_kernel(const bf16_t* __restrict__ Q,
                                                   const bf16_t* __restrict__ K,
                                                   const bf16_t* __restrict__ Vt,
                                                   bf16_t* __restrict__ O) {
    __shared__ bf16_t Ks[2][64 * 128];   // [kv row][d], swizzled chunks
    __shared__ bf16_t Vs[2][128 * 64];   // [d][kv], swizzled chunks
    __shared__ bf16_t Pl[8][16 * PLD];
    const int tid = threadIdx.x;
    const int lane = tid & 63, w = tid >> 6;   // w: 0..7
    const int bid = blockIdx.x;
    const int h = bid & 31;
    const int x = bid >> 5;              // 0..7
    const int wg = w >> 2, wi = w & 3;
    const int qtile = wg == 0 ? x : 15 - x;
    const int qb = qtile * 128 + wi * 32;      // wave's 32 q rows
    const int kv = h >> 2;               // N_REP = 4
    const int g = lane >> 4, c16 = lane & 15;
    const int c7 = c16 & 7;
    const bf16_t* Qh = Q + (size_t)h * S_LEN * HD;
    const bf16_t* Kh = K + (size_t)kv * S_LEN * HD;
    const bf16_t* Vh = Vt + (size_t)kv * HD * S_LEN;
    bf16_t* P = Pl[w];

    auto stage = [&](int buf, int kb) {
        bf16_t* Kd = Ks[buf];
        bf16_t* Vd = Vs[buf];
#pragma unroll
        for (int j = 0; j < 2; ++j) {
            int i = w * 2 + j;           // 16 instrs across 8 waves
            {   // K: instr covers 4 rows of 256B; lane l -> row 4i+(l>>4), chunk l&15
                int row = 4 * i + (lane >> 4);
                int sc = (lane & 15) ^ (row & 7);
                gload_lds16(Kh + (size_t)(kb + row) * HD + sc * 8, Kd + i * 512);
            }
            {   // V: instr covers 8 rows of 128B; lane l -> row 8i+(l>>3), chunk l&7
                int row = 8 * i + (lane >> 3);
                int sc = (lane & 7) ^ ((lane >> 3) & 7);
                gload_lds16(Vh + (size_t)row * S_LEN + kb + sc * 8, Vd + i * 512);
            }
        }
    };

    bf16x8 qf[2][4];
#pragma unroll
    for (int rg = 0; rg < 2; ++rg)
#pragma unroll
        for (int c = 0; c < 4; ++c)
            qf[rg][c] = *(const bf16x8*)(Qh + (size_t)(qb + rg * 16 + c16) * HD + c * 32 + g * 8);

    bf16x8 ones;
#pragma unroll
    for (int j = 0; j < 8; ++j) ones[j] = (bf16_t)1.0f;

    f32x4 acc_o[2][8];
#pragma unroll
    for (int rg = 0; rg < 2; ++rg)
#pragma unroll
        for (int dt = 0; dt < 8; ++dt) acc_o[rg][dt] = (f32x4){0.f, 0.f, 0.f, 0.f};
    f32x4 acc_l[2] = {(f32x4){0.f, 0.f, 0.f, 0.f}, (f32x4){0.f, 0.f, 0.f, 0.f}};
    float m[2][4];
#pragma unroll
    for (int rg = 0; rg < 2; ++rg)
#pragma unroll
        for (int r = 0; r < 4; ++r) m[rg][r] = -1e30f;

    const int nkt = 32 - 2 * x;
    stage(0, 0);
    __syncthreads();
    int cur = 0;

    bf16x8 pf[2][2];
    for (int kt = 0; kt < nkt; ++kt) {
        if (kt + 1 < nkt) stage(cur ^ 1, (kt + 1) * 64);
        const int kb = kt * 64;
        const bf16_t* Kb = Ks[cur];
        const bf16_t* Vb = Vs[cur];

        if (kb <= qb + 31) {             // wave-active
            const bool diag = (kb + 63 > qb);

            f32x4 sacc[2][4];
#pragma unroll
            for (int rg = 0; rg < 2; ++rg)
#pragma unroll
                for (int t = 0; t < 4; ++t) sacc[rg][t] = (f32x4){0.f, 0.f, 0.f, 0.f};
#pragma unroll
            for (int t = 0; t < 4; ++t) {
                const bf16_t* krow = Kb + (t * 16 + c16) * 128;
#pragma unroll
                for (int cc = 0; cc < 4; ++cc) {
                    bf16x8 kf = *(const bf16x8*)(krow + (((cc * 4 + g) ^ c7) * 8));
                    sacc[0][t] = __builtin_amdgcn_mfma_f32_16x16x32_bf16(qf[0][cc], kf, sacc[0][t], 0, 0, 0);
                    sacc[1][t] = __builtin_amdgcn_mfma_f32_16x16x32_bf16(qf[1][cc], kf, sacc[1][t], 0, 0, 0);
                }
            }
#pragma unroll
            for (int rg = 0; rg < 2; ++rg) {
                float p[4][4], mxr[4];
#pragma unroll
                for (int r = 0; r < 4; ++r) {
                    int qq = qb + rg * 16 + g * 4 + r;
#pragma unroll
                    for (int t = 0; t < 4; ++t) {
                        float sv = sacc[rg][t][r];
                        if (diag && (kb + t * 16 + c16 > qq)) sv = -1e30f;
                        p[t][r] = sv;
                    }
                    float mx = fmaxf(fmaxf(p[0][r], p[1][r]), fmaxf(p[2][r], p[3][r]));
                    mx = fmaxf(mx, __shfl_xor(mx, 1));
                    mx = fmaxf(mx, __shfl_xor(mx, 2));
                    mx = fmaxf(mx, __shfl_xor(mx, 4));
                    mx = fmaxf(mx, __shfl_xor(mx, 8));
                    mxr[r] = mx;
                }
                bool resc = false;
#pragma unroll
                for (int r = 0; r < 4; ++r) resc = resc || (mxr[r] > m[rg][r] + 8.f);
                if (__any(resc)) {
#pragma unroll
                    for (int r = 0; r < 4; ++r) {
                        float mn = fmaxf(m[rg][r], mxr[r]);
                        float al = fast_exp2(m[rg][r] - mn);
                        m[rg][r] = mn;
                        acc_l[rg][r] *= al;
#pragma unroll
                        for (int dt = 0; dt < 8; ++dt) acc_o[rg][dt][r] *= al;
                    }
                }
#pragma unroll
                for (int r = 0; r < 4; ++r)
#pragma unroll
                    for (int t = 0; t < 4; ++t)
                        p[t][r] = fast_exp2(p[t][r] - m[rg][r]);
#pragma unroll
                for (int t = 0; t < 4; ++t)
#pragma unroll
                    for (int r = 0; r < 4; ++r)
                        P[(g * 4 + r) * PLD + t * 16 + c16] = (bf16_t)p[t][r];
                pf[rg][0] = *(const bf16x8*)(P + c16 * PLD + g * 8);
                pf[rg][1] = *(const bf16x8*)(P + c16 * PLD + 32 + g * 8);
            }
            acc_l[0] = __builtin_amdgcn_mfma_f32_16x16x32_bf16(pf[0][0], ones, acc_l[0], 0, 0, 0);
            acc_l[0] = __builtin_amdgcn_mfma_f32_16x16x32_bf16(pf[0][1], ones, acc_l[0], 0, 0, 0);
            acc_l[1] = __builtin_amdgcn_mfma_f32_16x16x32_bf16(pf[1][0], ones, acc_l[1], 0, 0, 0);
            acc_l[1] = __builtin_amdgcn_mfma_f32_16x16x32_bf16(pf[1][1], ones, acc_l[1], 0, 0, 0);
#pragma unroll
            for (int dt = 0; dt < 8; ++dt) {
                const bf16_t* vrow = Vb + (dt * 16 + c16) * 64;
                bf16x8 vf0 = *(const bf16x8*)(vrow + ((g ^ c7) * 8));
                bf16x8 vf1 = *(const bf16x8*)(vrow + (((4 + g) ^ c7) * 8));
                acc_o[0][dt] = __builtin_amdgcn_mfma_f32_16x16x32_bf16(pf[0][0], vf0, acc_o[0][dt], 0, 0, 0);
                acc_o[0][dt] = __builtin_amdgcn_mfma_f32_16x16x32_bf16(pf[0][1], vf1, acc_o[0][dt], 0, 0, 0);
                acc_o[1][dt] = __builtin_amdgcn_mfma_f32_16x16x32_bf16(pf[1][0], vf0, acc_o[1][dt], 0, 0, 0);
                acc_o[1][dt] = __builtin_amdgcn_mfma_f32_16x16x32_bf16(pf[1][1], vf1, acc_o[1][dt], 0, 0, 0);
            }
        }
        __syncthreads();
        cur ^= 1;
    }
#pragma unroll
    for (int rg = 0; rg < 2; ++rg) {
        float inv_l[4];
#pragma unroll
        for (int r = 0; r < 4; ++r) inv_l[r] = 1.f / acc_l[rg][r];
#pragma unroll
        for (int dt = 0; dt < 8; ++dt)
#pragma unroll
            for (int r = 0; r < 4; ++r)
                O[(size_t)(qb + rg * 16 + g * 4 + r) * HIDDEN + h * HD + dt * 16 + c16] =
                    (bf16_t)(acc_o[rg][dt][r] * inv_l[r]);
    }
}

// ---------------- host ----------------
extern "C" void kernel_launch(void* const* d_in, const int* in_sizes, int n_in,
                              void* d_out, int out_size, void* d_ws, size_t ws_size,
                              hipStream_t stream) {
    const float* hs = (const float*)d_in[0];
    const float* Wq = (const float*)d_in[1];
    const float* Wk = (const float*)d_in[2];
    const float* Wv = (const float*)d_in[3];
    const float* Wo = (const float*)d_in[4];
    const int* pos = (const int*)d_in[6];
    float* out = (float*)d_out;

    char* ws = (char*)d_ws;
    size_t off = 0;
    auto alloc = [&](size_t bytes) -> void* {
        void* p = ws + off;
        off += (bytes + 255) & ~(size_t)255;
        return p;
    };
    bf16_t* hB    = (bf16_t*)alloc((size_t)S_LEN * HIDDEN * 2);
    bf16_t* WqkvT = (bf16_t*)alloc((size_t)NQKV * HIDDEN * 2);   // [6144][4096]
    bf16_t* WoT   = (bf16_t*)alloc((size_t)HIDDEN * HIDDEN * 2);
    bf16_t* QKV   = (bf16_t*)alloc((size_t)S_LEN * NQKV * 2);    // [2048][6144] bf16
    bf16_t* Qr    = (bf16_t*)alloc((size_t)NH * S_LEN * HD * 2);
    bf16_t* Kr    = (bf16_t*)alloc((size_t)NKV * S_LEN * HD * 2);
    bf16_t* Vt    = (bf16_t*)alloc((size_t)NKV * HD * S_LEN * 2);
    bf16_t* Oat   = (bf16_t*)alloc((size_t)S_LEN * HIDDEN * 2);

    // 1. cast hidden to bf16
    cast_bf16_kernel<<<2048, 256, 0, stream>>>(hs, hB, S_LEN * HIDDEN / 4);
    // 2. transpose-cast weights into fused [6144][4096] (64x64 tiles, vectorized)
    transpose_cast_kernel<<<dim3(HIDDEN / 64, HIDDEN / 64), 256, 0, stream>>>(Wq, WqkvT, HIDDEN, HIDDEN);
    transpose_cast_kernel<<<dim3(1024 / 64, HIDDEN / 64), 256, 0, stream>>>(Wk, WqkvT + (size_t)4096 * HIDDEN, 1024, HIDDEN);
    transpose_cast_kernel<<<dim3(1024 / 64, HIDDEN / 64), 256, 0, stream>>>(Wv, WqkvT + (size_t)5120 * HIDDEN, 1024, HIDDEN);
    transpose_cast_kernel<<<dim3(HIDDEN / 64, HIDDEN / 64), 256, 0, stream>>>(Wo, WoT, HIDDEN, HIDDEN);
    // 3. fused QKV projection -> bf16 [2048][6144]; BN=192 -> 512 blocks = exactly 2/CU
    gemm_ring_kernel<192, bf16_t><<<(S_LEN / 128) * (NQKV / 192), 512, 0, stream>>>(hB, WqkvT, QKV, S_LEN, NQKV, HIDDEN);
    // 4. RoPE; Q scale = log2(e)/sqrt(128) for exp2-domain softmax
    rope_kernel<<<(S_LEN * NH * 64 + 255) / 256, 256, 0, stream>>>(QKV, Qr, pos, NH, NQKV, 0.1275174310f);
    rope_kernel<<<(S_LEN * NKV * 64 + 255) / 256, 256, 0, stream>>>(QKV + 4096, Kr, pos, NKV, NQKV, 1.0f);
    // 5. V transpose: bf16 [S][1024] (stride 6144) -> [1024][2048] == [NKV][128][S]
    transpose_bf16_kernel<<<dim3(1024 / 64, S_LEN / 64), 256, 0, stream>>>(QKV + 5120, Vt, NQKV, S_LEN);
    // 6. flash attention: 256 blocks (8 mirrored-pair segments x 32 heads), 1/CU
    attn_kernel<<<256, 512, 0, stream>>>(Qr, Kr, Vt, Oat);
    // 7. output projection (fp32 out); BN=128 -> 512 blocks = exactly 2/CU
    gemm_ring_kernel<128, float><<<(S_LEN / 128) * (HIDDEN / 128), 512, 0, stream>>>(Oat, WoT, out, S_LEN, HIDDEN, HIDDEN);
}

// Round 15
// 347.124 us; speedup vs baseline: 1.2687x; 1.0537x over previous
//
#include <hip/hip_runtime.h>
#include <hip/hip_bf16.h>

#define S_LEN 2048
#define HIDDEN 4096
#define NH 32
#define NKV 8
#define HD 128
#define NQKV 6144   // NH*HD + 2*NKV*HD

typedef __bf16 bf16_t;
typedef __bf16 bf16x8 __attribute__((ext_vector_type(8)));
typedef __bf16 bf16x4 __attribute__((ext_vector_type(4)));
typedef float f32x4 __attribute__((ext_vector_type(4)));

typedef __attribute__((address_space(1))) void gvoid;
typedef __attribute__((address_space(3))) void lvoid;

__device__ __forceinline__ void gload_lds16(const void* g, void* l) {
    __builtin_amdgcn_global_load_lds((gvoid*)g, (lvoid*)l, 16, 0, 0);
}

__device__ __forceinline__ float fast_exp2(float x) {
    return __builtin_amdgcn_exp2f(x);   // v_exp_f32 (2^x native)
}

__device__ __forceinline__ unsigned int pack2_bf16(float lo, float hi) {
    bf16_t l = (bf16_t)lo, h = (bf16_t)hi;
    unsigned short lu, hu;
    __builtin_memcpy(&lu, &l, 2);
    __builtin_memcpy(&hu, &h, 2);
    return ((unsigned int)hu << 16) | (unsigned int)lu;
}

// ---------------- cast fp32 -> bf16 (vectorized) ----------------
__global__ void cast_bf16_kernel(const float* __restrict__ in, bf16_t* __restrict__ out, int n4) {
    int stride = gridDim.x * blockDim.x;
    for (int idx = blockIdx.x * blockDim.x + threadIdx.x; idx < n4; idx += stride) {
        float4 v = ((const float4*)in)[idx];
        bf16x4 o;
        o.x = (bf16_t)v.x; o.y = (bf16_t)v.y; o.z = (bf16_t)v.z; o.w = (bf16_t)v.w;
        ((bf16x4*)out)[idx] = o;
    }
}

// ---------------- fast transpose+cast: fp32 in[R][C] (ldin) -> bf16 out[C][R] (ldout) ----------------
__global__ __launch_bounds__(256) void transpose_cast_kernel(const float* __restrict__ in,
                                                             bf16_t* __restrict__ out,
                                                             int ldin, int ldout) {
    __shared__ unsigned int t2[64][34];
    const int c0 = blockIdx.x * 64, r0 = blockIdx.y * 64;
    const int t = threadIdx.x;
    const int tx4 = t & 15, tp = t >> 4;
#pragma unroll
    for (int i = 0; i < 2; ++i) {
        int rp = tp + i * 16;
        const float* p0 = &in[(size_t)(r0 + 2 * rp) * ldin + c0 + tx4 * 4];
        float4 a = *(const float4*)p0;
        float4 b = *(const float4*)(p0 + ldin);
        t2[tx4 * 4 + 0][rp] = pack2_bf16(a.x, b.x);
        t2[tx4 * 4 + 1][rp] = pack2_bf16(a.y, b.y);
        t2[tx4 * 4 + 2][rp] = pack2_bf16(a.z, b.z);
        t2[tx4 * 4 + 3][rp] = pack2_bf16(a.w, b.w);
    }
    __syncthreads();
    const int q = t & 3, cc = t >> 2;
    uint2 v0 = *(const uint2*)&t2[cc][q * 8 + 0];
    uint2 v1 = *(const uint2*)&t2[cc][q * 8 + 2];
    uint2 v2 = *(const uint2*)&t2[cc][q * 8 + 4];
    uint2 v3 = *(const uint2*)&t2[cc][q * 8 + 6];
    bf16_t* o = &out[(size_t)(c0 + cc) * ldout + r0 + q * 16];
    *(uint4*)o = make_uint4(v0.x, v0.y, v1.x, v1.y);
    *(uint4*)(o + 8) = make_uint4(v2.x, v2.y, v3.x, v3.y);
}

// ---------------- fast transpose bf16 -> bf16 (same scheme, bf16x4 loads) ----------------
__global__ __launch_bounds__(256) void transpose_bf16_kernel(const bf16_t* __restrict__ in,
                                                             bf16_t* __restrict__ out,
                                                             int ldin, int ldout) {
    __shared__ unsigned int t2[64][34];
    const int c0 = blockIdx.x * 64, r0 = blockIdx.y * 64;
    const int t = threadIdx.x;
    const int tx4 = t & 15, tp = t >> 4;
#pragma unroll
    for (int i = 0; i < 2; ++i) {
        int rp = tp + i * 16;
        const bf16_t* p0 = &in[(size_t)(r0 + 2 * rp) * ldin + c0 + tx4 * 4];
        bf16x4 a = *(const bf16x4*)p0;
        bf16x4 b = *(const bf16x4*)(p0 + ldin);
#pragma unroll
        for (int k2 = 0; k2 < 4; ++k2) {
            unsigned short lu, hu;
            bf16_t la = a[k2], hb = b[k2];
            __builtin_memcpy(&lu, &la, 2);
            __builtin_memcpy(&hu, &hb, 2);
            t2[tx4 * 4 + k2][rp] = ((unsigned int)hu << 16) | (unsigned int)lu;
        }
    }
    __syncthreads();
    const int q = t & 3, cc = t >> 2;
    uint2 v0 = *(const uint2*)&t2[cc][q * 8 + 0];
    uint2 v1 = *(const uint2*)&t2[cc][q * 8 + 2];
    uint2 v2 = *(const uint2*)&t2[cc][q * 8 + 4];
    uint2 v3 = *(const uint2*)&t2[cc][q * 8 + 6];
    bf16_t* o = &out[(size_t)(c0 + cc) * ldout + r0 + q * 16];
    *(uint4*)o = make_uint4(v0.x, v0.y, v1.x, v1.y);
    *(uint4*)(o + 8) = make_uint4(v2.x, v2.y, v3.x, v3.y);
}

// ---------------- ring-3 counted-vmcnt GEMM (unchanged from round 14) ----------------
template<int BN, typename OutT>
__global__ __launch_bounds__(512, 2) void gemm_ring_kernel(const bf16_t* __restrict__ A,
                                                           const bf16_t* __restrict__ Bt,
                                                           OutT* __restrict__ C,
                                                           int M, int N, int K) {
    constexpr int NF = BN / 64;          // per-wave n frags
    constexpr int VMN = (BN == 256) ? 3 : 2;
    __shared__ bf16_t As[3][128 * 32];
    __shared__ bf16_t Bs[3][BN * 32];
    const int tid = threadIdx.x;
    const int lane = tid & 63, w = tid >> 6;
    const int wm = w >> 2, wn = w & 3;
    const int g = lane >> 4, c16 = lane & 15;
    const int srow = lane >> 2;
    const int scg = ((lane & 3) ^ ((lane >> 3) & 3)) * 8;
    const int rdc = (g ^ ((c16 >> 1) & 3)) * 8;

    const int nbm = M / 128;
    const int cpx = gridDim.x >> 3;
    const int bid = blockIdx.x;
    const int swz = (bid & 7) * cpx + (bid >> 3);
    const int bm = swz % nbm, bn = swz / nbm;

    const bf16_t* Ab = A + (size_t)(bm * 128) * K;
    const bf16_t* Bb = Bt + (size_t)bn * BN * K;

    auto stage = [&](int slot, int kt) {
        const bf16_t* Ak = Ab + (size_t)kt * 32;
        const bf16_t* Bk = Bb + (size_t)kt * 32;
        if constexpr (BN == 256) {
            int rb = 16 * w;
            gload_lds16(Ak + (size_t)(rb + srow) * K + scg, &As[slot][rb * 32]);
#pragma unroll
            for (int j = 0; j < 2; ++j) {
                int rb2 = 32 * w + 16 * j;
                gload_lds16(Bk + (size_t)(rb2 + srow) * K + scg, &Bs[slot][rb2 * 32]);
            }
        } else if constexpr (BN == 192) {
            if (w < 4) {
#pragma unroll
                for (int j = 0; j < 3; ++j) {
                    int rb = 48 * w + 16 * j;
                    gload_lds16(Bk + (size_t)(rb + srow) * K + scg, &Bs[slot][rb * 32]);
                }
            } else {
#pragma unroll
                for (int j = 0; j < 2; ++j) {
                    int rb = 32 * (w - 4) + 16 * j;
                    gload_lds16(Ak + (size_t)(rb + srow) * K + scg, &As[slot][rb * 32]);
                }
            }
        } else {   // BN == 128
            int rb = 16 * w;
            gload_lds16(Ak + (size_t)(rb + srow) * K + scg, &As[slot][rb * 32]);
            gload_lds16(Bk + (size_t)(rb + srow) * K + scg, &Bs[slot][rb * 32]);
        }
    };

    f32x4 acc[4][NF];
#pragma unroll
    for (int i = 0; i < 4; ++i)
#pragma unroll
        for (int j = 0; j < NF; ++j)
            acc[i][j] = (f32x4){0.f, 0.f, 0.f, 0.f};

    const int NT = K / 32;
    stage(0, 0);
    stage(1, 1);

    int slot = 0, slot2 = 2;
    for (int t = 0; t < NT; ++t) {
        asm volatile("s_waitcnt vmcnt(%0)" :: "n"(VMN) : "memory");
        __builtin_amdgcn_s_barrier();
        __builtin_amdgcn_sched_barrier(0);
        __builtin_amdgcn_s_setprio(1);

        bf16x8 af[4], bf[NF];
#pragma unroll
        for (int i = 0; i < 4; ++i) {
            int arow = wm * 64 + i * 16 + c16;
            af[i] = *(const bf16x8*)&As[slot][arow * 32 + rdc];
        }
#pragma unroll
        for (int j = 0; j < NF; ++j) {
            int brow = wn * (BN / 4) + j * 16 + c16;
            bf[j] = *(const bf16x8*)&Bs[slot][brow * 32 + rdc];
        }
        int nk = t + 2;
        if (nk >= NT) nk -= NT;        // wrap-stage: keeps ledger uniform, never read
        stage(slot2, nk);

#pragma unroll
        for (int i = 0; i < 4; ++i)
#pragma unroll
            for (int j = 0; j < NF; ++j)
                acc[i][j] = __builtin_amdgcn_mfma_f32_16x16x32_bf16(af[i], bf[j], acc[i][j], 0, 0, 0);
        __builtin_amdgcn_s_setprio(0);

        slot = (slot + 1) % 3;
        slot2 = (slot2 + 1) % 3;
    }

#pragma unroll
    for (int mi = 0; mi < 4; ++mi)
#pragma unroll
        for (int ni = 0; ni < NF; ++ni) {
            int col = bn * BN + wn * (BN / 4) + ni * 16 + c16;
#pragma unroll
            for (int r = 0; r < 4; ++r) {
                int row = bm * 128 + wm * 64 + mi * 16 + g * 4 + r;
                C[(size_t)row * N + col] = (OutT)acc[mi][ni][r];
            }
        }
}

// ---------------- RoPE: in bf16 [S][ld] (head block at col h*128) -> out bf16 [H][S][128] ----------------
__global__ void rope_kernel(const bf16_t* __restrict__ in, bf16_t* __restrict__ out,
                            const int* __restrict__ pos, int H, int ld, float scale) {
    int idx = blockIdx.x * blockDim.x + threadIdx.x;
    int total = S_LEN * H * 64;
    if (idx >= total) return;
    int d = idx & 63;
    int h = (idx >> 6) % H;
    int s = idx / (64 * H);
    const bf16_t* base = in + (size_t)s * ld + h * HD;
    float x0 = (float)base[d], x1 = (float)base[d + 64];
    float p = (float)pos[s];
    float invf = fast_exp2(-0.20762050593046935f * (float)d);  // log2(10000)/64
    float f = p * invf;
    float sn, cs;
    __sincosf(f, &sn, &cs);
    float o0 = (x0 * cs - x1 * sn) * scale;
    float o1 = (x1 * cs + x0 * sn) * scale;
    bf16_t* ob = out + ((size_t)h * S_LEN + s) * HD;
    ob[d] = (bf16_t)o0;
    ob[d + 64] = (bf16_t)o1;
}

// ---------------- flash attention v5: kv-split + sequential mirrored q-tiles ----------------
// Grid 256 (x 0..7 x 32 heads), 512 threads, 1 block/CU. Block processes q-tile x then
// q-tile 15-x SEQUENTIALLY (uniform 17 rounds total). Within a q-tile (128 rows):
// waves 0-3 (grp 0) take EVEN 64-kv tiles, waves 4-7 (grp 1) take ODD tiles — all 8 waves
// busy every round, each with 32 q-rows and private online-softmax state; partials merged
// once per q-tile via LDS ([idx][lane] layout, conflict-free). K/V window: 4 slots (64KB+64KB);
// round r consumes tiles {2r,2r+1}, stages {2r+2,2r+3} (disjoint slots, one barrier/round).
// LDS 145.4 KB -> 1 block/CU. ones-MFMA row-sum + defer-max THR=8 retained.
#define PLD 68
__global__ __launch_bounds__(512) void attn_kernel(const bf16_t* __restrict__ Q,
                                                   const bf16_t* __restrict__ K,
                                                   const bf16_t* __restrict__ Vt,
                                                   bf16_t* __restrict__ O) {
    __shared__ bf16_t Ks[4][64 * 128];   // [kv row][d], swizzled chunks
    __shared__ bf16_t Vs[4][128 * 64];   // [d][kv], swizzled chunks
    __shared__ bf16_t Pl[8][16 * PLD];
    const int tid = threadIdx.x;
    const int lane = tid & 63, w = tid >> 6;   // w: 0..7
    const int bid = blockIdx.x;
    const int h = bid & 31;
    const int x = bid >> 5;              // 0..7
    const int grp = w >> 2, wi = w & 3;
    const int kv = h >> 2;               // N_REP = 4
    const int quad = lane >> 4, c16 = lane & 15;
    const int c7 = c16 & 7;
    const bf16_t* Qh = Q + (size_t)h * S_LEN * HD;
    const bf16_t* Kh = K + (size_t)kv * S_LEN * HD;
    const bf16_t* Vh = Vt + (size_t)kv * HD * S_LEN;
    bf16_t* P = Pl[w];

    auto stage = [&](int slot, int kb) {
        bf16_t* Kd = Ks[slot];
        bf16_t* Vd = Vs[slot];
#pragma unroll
        for (int j = 0; j < 2; ++j) {
            int i = w * 2 + j;           // 16 instrs across 8 waves
            {   // K: instr covers 4 rows of 256B
                int row = 4 * i + (lane >> 4);
                int sc = (lane & 15) ^ (row & 7);
                gload_lds16(Kh + (size_t)(kb + row) * HD + sc * 8, Kd + i * 512);
            }
            {   // V: instr covers 8 rows of 128B
                int row = 8 * i + (lane >> 3);
                int sc = (lane & 7) ^ ((lane >> 3) & 7);
                gload_lds16(Vh + (size_t)row * S_LEN + kb + sc * 8, Vd + i * 512);
            }
        }
    };

    bf16x8 ones;
#pragma unroll
    for (int j = 0; j < 8; ++j) ones[j] = (bf16_t)1.0f;

    for (int ph = 0; ph < 2; ++ph) {
        const int qt = (ph == 0) ? x : 15 - x;
        const int R = qt + 1;            // rounds for this q-tile
        const int qb = qt * 128 + wi * 32;

        bf16x8 qf[2][4];
#pragma unroll
        for (int rg = 0; rg < 2; ++rg)
#pragma unroll
            for (int c = 0; c < 4; ++c)
                qf[rg][c] = *(const bf16x8*)(Qh + (size_t)(qb + rg * 16 + c16) * HD + c * 32 + quad * 8);

        f32x4 acc_o[2][8];
#pragma unroll
        for (int rg = 0; rg < 2; ++rg)
#pragma unroll
            for (int dt = 0; dt < 8; ++dt) acc_o[rg][dt] = (f32x4){0.f, 0.f, 0.f, 0.f};
        f32x4 acc_l[2] = {(f32x4){0.f, 0.f, 0.f, 0.f}, (f32x4){0.f, 0.f, 0.f, 0.f}};
        float m[2][4];
#pragma unroll
        for (int rg = 0; rg < 2; ++rg)
#pragma unroll
            for (int r = 0; r < 4; ++r) m[rg][r] = -1e30f;

        stage(0, 0);
        stage(1, 64);
        __syncthreads();

        for (int r = 0; r < R; ++r) {
            int jn0 = 2 * r + 2, jn1 = 2 * r + 3;
            if (jn0 < 2 * R) stage(jn0 & 3, jn0 * 64);
            if (jn1 < 2 * R) stage(jn1 & 3, jn1 * 64);

            const int j = 2 * r + grp;   // this group's kv tile
            const int kb = j * 64;
            const bf16_t* Kb = Ks[j & 3];
            const bf16_t* Vb = Vs[j & 3];

            if (kb <= qb + 31) {         // wave-active
                const bool diag = (kb + 63 > qb);

                f32x4 sacc[2][4];
#pragma unroll
                for (int rg = 0; rg < 2; ++rg)
#pragma unroll
                    for (int t = 0; t < 4; ++t) sacc[rg][t] = (f32x4){0.f, 0.f, 0.f, 0.f};
#pragma unroll
                for (int t = 0; t < 4; ++t) {
                    const bf16_t* krow = Kb + (t * 16 + c16) * 128;
#pragma unroll
                    for (int cc = 0; cc < 4; ++cc) {
                        bf16x8 kf = *(const bf16x8*)(krow + (((cc * 4 + quad) ^ c7) * 8));
                        sacc[0][t] = __builtin_amdgcn_mfma_f32_16x16x32_bf16(qf[0][cc], kf, sacc[0][t], 0, 0, 0);
                        sacc[1][t] = __builtin_amdgcn_mfma_f32_16x16x32_bf16(qf[1][cc], kf, sacc[1][t], 0, 0, 0);
                    }
                }
                bf16x8 pf[2][2];
#pragma unroll
                for (int rg = 0; rg < 2; ++rg) {
                    float p[4][4], mxr[4];
#pragma unroll
                    for (int r4 = 0; r4 < 4; ++r4) {
                        int qq = qb + rg * 16 + quad * 4 + r4;
#pragma unroll
                        for (int t = 0; t < 4; ++t) {
                            float sv = sacc[rg][t][r4];
                            if (diag && (kb + t * 16 + c16 > qq)) sv = -1e30f;
                            p[t][r4] = sv;
                        }
                        float mx = fmaxf(fmaxf(p[0][r4], p[1][r4]), fmaxf(p[2][r4], p[3][r4]));
                        mx = fmaxf(mx, __shfl_xor(mx, 1));
                        mx = fmaxf(mx, __shfl_xor(mx, 2));
                        mx = fmaxf(mx, __shfl_xor(mx, 4));
                        mx = fmaxf(mx, __shfl_xor(mx, 8));
                        mxr[r4] = mx;
                    }
                    bool resc = false;
#pragma unroll
                    for (int r4 = 0; r4 < 4; ++r4) resc = resc || (mxr[r4] > m[rg][r4] + 8.f);
                    if (__any(resc)) {
#pragma unroll
                        for (int r4 = 0; r4 < 4; ++r4) {
                            float mn = fmaxf(m[rg][r4], mxr[r4]);
                            float al = fast_exp2(m[rg][r4] - mn);
                            m[rg][r4] = mn;
                            acc_l[rg][r4] *= al;
#pragma unroll
                            for (int dt = 0; dt < 8; ++dt) acc_o[rg][dt][r4] *= al;
                        }
                    }
#pragma unroll
                    for (int r4 = 0; r4 < 4; ++r4)
#pragma unroll
                        for (int t = 0; t < 4; ++t)
                            p[t][r4] = fast_exp2(p[t][r4] - m[rg][r4]);
#pragma unroll
                    for (int t = 0; t < 4; ++t)
#pragma unroll
                        for (int r4 = 0; r4 < 4; ++r4)
                            P[(quad * 4 + r4) * PLD + t * 16 + c16] = (bf16_t)p[t][r4];
                    pf[rg][0] = *(const bf16x8*)(P + c16 * PLD + quad * 8);
                    pf[rg][1] = *(const bf16x8*)(P + c16 * PLD + 32 + quad * 8);
                }
                acc_l[0] = __builtin_amdgcn_mfma_f32_16x16x32_bf16(pf[0][0], ones, acc_l[0], 0, 0, 0);
                acc_l[0] = __builtin_amdgcn_mfma_f32_16x16x32_bf16(pf[0][1], ones, acc_l[0], 0, 0, 0);
                acc_l[1] = __builtin_amdgcn_mfma_f32_16x16x32_bf16(pf[1][0], ones, acc_l[1], 0, 0, 0);
                acc_l[1] = __builtin_amdgcn_mfma_f32_16x16x32_bf16(pf[1][1], ones, acc_l[1], 0, 0, 0);
#pragma unroll
                for (int dt = 0; dt < 8; ++dt) {
                    const bf16_t* vrow = Vb + (dt * 16 + c16) * 64;
                    bf16x8 vf0 = *(const bf16x8*)(vrow + ((quad ^ c7) * 8));
                    bf16x8 vf1 = *(const bf16x8*)(vrow + (((4 + quad) ^ c7) * 8));
                    acc_o[0][dt] = __builtin_amdgcn_mfma_f32_16x16x32_bf16(pf[0][0], vf0, acc_o[0][dt], 0, 0, 0);
                    acc_o[0][dt] = __builtin_amdgcn_mfma_f32_16x16x32_bf16(pf[0][1], vf1, acc_o[0][dt], 0, 0, 0);
                    acc_o[1][dt] = __builtin_amdgcn_mfma_f32_16x16x32_bf16(pf[1][0], vf0, acc_o[1][dt], 0, 0, 0);
                    acc_o[1][dt] = __builtin_amdgcn_mfma_f32_16x16x32_bf16(pf[1][1], vf1, acc_o[1][dt], 0, 0, 0);
                }
            }
            __syncthreads();
        }

        // ---- merge the two kv-split groups (grp1 -> LDS, grp0 combines & writes O) ----
        // scratch layout [idx][wi*64+lane] (f32): lanes -> distinct banks, conflict-free.
        float* s0 = (float*)&Ks[0][0];   // 48 idx x 256 x 4B = 49KB <= 64KB
        float* s1 = (float*)&Vs[0][0];   // 32 idx x 256 x 4B = 32KB <= 64KB
        const int sl = wi * 64 + lane;
        if (grp == 1) {
#pragma unroll
            for (int rg = 0; rg < 2; ++rg)
#pragma unroll
                for (int r4 = 0; r4 < 4; ++r4) {
                    s0[(rg * 4 + r4) * 256 + sl] = m[rg][r4];
                    s0[(8 + rg * 4 + r4) * 256 + sl] = acc_l[rg][r4];
                }
#pragma unroll
            for (int dt = 0; dt < 8; ++dt)
#pragma unroll
                for (int r4 = 0; r4 < 4; ++r4) {
                    s0[(16 + dt * 4 + r4) * 256 + sl] = acc_o[0][dt][r4];
                    s1[(dt * 4 + r4) * 256 + sl] = acc_o[1][dt][r4];
                }
        }
        __syncthreads();
        if (grp == 0) {
#pragma unroll
            for (int rg = 0; rg < 2; ++rg)
#pragma unroll
                for (int r4 = 0; r4 < 4; ++r4) {
                    float m1 = s0[(rg * 4 + r4) * 256 + sl];
                    float l1 = s0[(8 + rg * 4 + r4) * 256 + sl];
                    float mm = fmaxf(m[rg][r4], m1);
                    float a0 = fast_exp2(m[rg][r4] - mm);
                    float a1 = fast_exp2(m1 - mm);
                    float ll = acc_l[rg][r4] * a0 + l1 * a1;
                    float inv = 1.f / ll;
                    bf16_t* orow = &O[(size_t)(qb + rg * 16 + quad * 4 + r4) * HIDDEN + h * HD];
#pragma unroll
                    for (int dt = 0; dt < 8; ++dt) {
                        float o1 = (rg == 0) ? s0[(16 + dt * 4 + r4) * 256 + sl]
                                             : s1[(dt * 4 + r4) * 256 + sl];
                        float val = (acc_o[rg][dt][r4] * a0 + o1 * a1) * inv;
                        orow[dt * 16 + c16] = (bf16_t)val;
                    }
                }
        }
        __syncthreads();                 // scratch free before next q-tile's staging
    }
}

// ---------------- host ----------------
extern "C" void kernel_launch(void* const* d_in, const int* in_sizes, int n_in,
                              void* d_out, int out_size, void* d_ws, size_t ws_size,
                              hipStream_t stream) {
    const float* hs = (const float*)d_in[0];
    const float* Wq = (const float*)d_in[1];
    const float* Wk = (const float*)d_in[2];
    const float* Wv = (const float*)d_in[3];
    const float* Wo = (const float*)d_in[4];
    const int* pos = (const int*)d_in[6];
    float* out = (float*)d_out;

    char* ws = (char*)d_ws;
    size_t off = 0;
    auto alloc = [&](size_t bytes) -> void* {
        void* p = ws + off;
        off += (bytes + 255) & ~(size_t)255;
        return p;
    };
    bf16_t* hB    = (bf16_t*)alloc((size_t)S_LEN * HIDDEN * 2);
    bf16_t* WqkvT = (bf16_t*)alloc((size_t)NQKV * HIDDEN * 2);   // [6144][4096]
    bf16_t* WoT   = (bf16_t*)alloc((size_t)HIDDEN * HIDDEN * 2);
    bf16_t* QKV   = (bf16_t*)alloc((size_t)S_LEN * NQKV * 2);    // [2048][6144] bf16
    bf16_t* Qr    = (bf16_t*)alloc((size_t)NH * S_LEN * HD * 2);
    bf16_t* Kr    = (bf16_t*)alloc((size_t)NKV * S_LEN * HD * 2);
    bf16_t* Vt    = (bf16_t*)alloc((size_t)NKV * HD * S_LEN * 2);
    bf16_t* Oat   = (bf16_t*)alloc((size_t)S_LEN * HIDDEN * 2);

    // 1. cast hidden to bf16
    cast_bf16_kernel<<<2048, 256, 0, stream>>>(hs, hB, S_LEN * HIDDEN / 4);
    // 2. transpose-cast weights into fused [6144][4096] (64x64 tiles, vectorized)
    transpose_cast_kernel<<<dim3(HIDDEN / 64, HIDDEN / 64), 256, 0, stream>>>(Wq, WqkvT, HIDDEN, HIDDEN);
    transpose_cast_kernel<<<dim3(1024 / 64, HIDDEN / 64), 256, 0, stream>>>(Wk, WqkvT + (size_t)4096 * HIDDEN, 1024, HIDDEN);
    transpose_cast_kernel<<<dim3(1024 / 64, HIDDEN / 64), 256, 0, stream>>>(Wv, WqkvT + (size_t)5120 * HIDDEN, 1024, HIDDEN);
    transpose_cast_kernel<<<dim3(HIDDEN / 64, HIDDEN / 64), 256, 0, stream>>>(Wo, WoT, HIDDEN, HIDDEN);
    // 3. fused QKV projection -> bf16 [2048][6144]; BN=192 -> 512 blocks = exactly 2/CU
    gemm_ring_kernel<192, bf16_t><<<(S_LEN / 128) * (NQKV / 192), 512, 0, stream>>>(hB, WqkvT, QKV, S_LEN, NQKV, HIDDEN);
    // 4. RoPE; Q scale = log2(e)/sqrt(128) for exp2-domain softmax
    rope_kernel<<<(S_LEN * NH * 64 + 255) / 256, 256, 0, stream>>>(QKV, Qr, pos, NH, NQKV, 0.1275174310f);
    rope_kernel<<<(S_LEN * NKV * 64 + 255) / 256, 256, 0, stream>>>(QKV + 4096, Kr, pos, NKV, NQKV, 1.0f);
    // 5. V transpose: bf16 [S][1024] (stride 6144) -> [1024][2048] == [NKV][128][S]
    transpose_bf16_kernel<<<dim3(1024 / 64, S_LEN / 64), 256, 0, stream>>>(QKV + 5120, Vt, NQKV, S_LEN);
    // 6. flash attention v5: 256 blocks (8 mirrored segments x 32 heads), 1/CU, 17 uniform rounds
    attn_kernel<<<256, 512, 0, stream>>>(Qr, Kr, Vt, Oat);
    // 7. output projection (fp32 out); BN=128 -> 512 blocks = exactly 2/CU
    gemm_ring_kernel<128, float><<<(S_LEN / 128) * (HIDDEN / 128), 512, 0, stream>>>(Oat, WoT, out, S_LEN, HIDDEN, HIDDEN);
}

// Round 16
// 334.579 us; speedup vs baseline: 1.3163x; 1.0375x over previous
//
#include <hip/hip_runtime.h>
#include <hip/hip_bf16.h>

#define S_LEN 2048
#define HIDDEN 4096
#define NH 32
#define NKV 8
#define HD 128
#define NQKV 6144   // NH*HD + 2*NKV*HD

typedef __bf16 bf16_t;
typedef __bf16 bf16x8 __attribute__((ext_vector_type(8)));
typedef __bf16 bf16x4 __attribute__((ext_vector_type(4)));
typedef float f32x4 __attribute__((ext_vector_type(4)));

typedef __attribute__((address_space(1))) void gvoid;
typedef __attribute__((address_space(3))) void lvoid;

__device__ __forceinline__ void gload_lds16(const void* g, void* l) {
    __builtin_amdgcn_global_load_lds((gvoid*)g, (lvoid*)l, 16, 0, 0);
}

__device__ __forceinline__ float fast_exp2(float x) {
    return __builtin_amdgcn_exp2f(x);   // v_exp_f32 (2^x native)
}

__device__ __forceinline__ unsigned int pack2_bf16(float lo, float hi) {
    bf16_t l = (bf16_t)lo, h = (bf16_t)hi;
    unsigned short lu, hu;
    __builtin_memcpy(&lu, &l, 2);
    __builtin_memcpy(&hu, &h, 2);
    return ((unsigned int)hu << 16) | (unsigned int)lu;
}

// ---------------- cast fp32 -> bf16 (vectorized) ----------------
__global__ void cast_bf16_kernel(const float* __restrict__ in, bf16_t* __restrict__ out, int n4) {
    int stride = gridDim.x * blockDim.x;
    for (int idx = blockIdx.x * blockDim.x + threadIdx.x; idx < n4; idx += stride) {
        float4 v = ((const float4*)in)[idx];
        bf16x4 o;
        o.x = (bf16_t)v.x; o.y = (bf16_t)v.y; o.z = (bf16_t)v.z; o.w = (bf16_t)v.w;
        ((bf16x4*)out)[idx] = o;
    }
}

// ---------------- fast transpose+cast: fp32 in[R][C] (ldin) -> bf16 out[C][R] (ldout) ----------------
__global__ __launch_bounds__(256) void transpose_cast_kernel(const float* __restrict__ in,
                                                             bf16_t* __restrict__ out,
                                                             int ldin, int ldout) {
    __shared__ unsigned int t2[64][34];
    const int c0 = blockIdx.x * 64, r0 = blockIdx.y * 64;
    const int t = threadIdx.x;
    const int tx4 = t & 15, tp = t >> 4;
#pragma unroll
    for (int i = 0; i < 2; ++i) {
        int rp = tp + i * 16;
        const float* p0 = &in[(size_t)(r0 + 2 * rp) * ldin + c0 + tx4 * 4];
        float4 a = *(const float4*)p0;
        float4 b = *(const float4*)(p0 + ldin);
        t2[tx4 * 4 + 0][rp] = pack2_bf16(a.x, b.x);
        t2[tx4 * 4 + 1][rp] = pack2_bf16(a.y, b.y);
        t2[tx4 * 4 + 2][rp] = pack2_bf16(a.z, b.z);
        t2[tx4 * 4 + 3][rp] = pack2_bf16(a.w, b.w);
    }
    __syncthreads();
    const int q = t & 3, cc = t >> 2;
    uint2 v0 = *(const uint2*)&t2[cc][q * 8 + 0];
    uint2 v1 = *(const uint2*)&t2[cc][q * 8 + 2];
    uint2 v2 = *(const uint2*)&t2[cc][q * 8 + 4];
    uint2 v3 = *(const uint2*)&t2[cc][q * 8 + 6];
    bf16_t* o = &out[(size_t)(c0 + cc) * ldout + r0 + q * 16];
    *(uint4*)o = make_uint4(v0.x, v0.y, v1.x, v1.y);
    *(uint4*)(o + 8) = make_uint4(v2.x, v2.y, v3.x, v3.y);
}

// ---------------- fast transpose bf16 -> bf16 (same scheme, bf16x4 loads) ----------------
__global__ __launch_bounds__(256) void transpose_bf16_kernel(const bf16_t* __restrict__ in,
                                                             bf16_t* __restrict__ out,
                                                             int ldin, int ldout) {
    __shared__ unsigned int t2[64][34];
    const int c0 = blockIdx.x * 64, r0 = blockIdx.y * 64;
    const int t = threadIdx.x;
    const int tx4 = t & 15, tp = t >> 4;
#pragma unroll
    for (int i = 0; i < 2; ++i) {
        int rp = tp + i * 16;
        const bf16_t* p0 = &in[(size_t)(r0 + 2 * rp) * ldin + c0 + tx4 * 4];
        bf16x4 a = *(const bf16x4*)p0;
        bf16x4 b = *(const bf16x4*)(p0 + ldin);
#pragma unroll
        for (int k2 = 0; k2 < 4; ++k2) {
            unsigned short lu, hu;
            bf16_t la = a[k2], hb = b[k2];
            __builtin_memcpy(&lu, &la, 2);
            __builtin_memcpy(&hu, &hb, 2);
            t2[tx4 * 4 + k2][rp] = ((unsigned int)hu << 16) | (unsigned int)lu;
        }
    }
    __syncthreads();
    const int q = t & 3, cc = t >> 2;
    uint2 v0 = *(const uint2*)&t2[cc][q * 8 + 0];
    uint2 v1 = *(const uint2*)&t2[cc][q * 8 + 2];
    uint2 v2 = *(const uint2*)&t2[cc][q * 8 + 4];
    uint2 v3 = *(const uint2*)&t2[cc][q * 8 + 6];
    bf16_t* o = &out[(size_t)(c0 + cc) * ldout + r0 + q * 16];
    *(uint4*)o = make_uint4(v0.x, v0.y, v1.x, v1.y);
    *(uint4*)(o + 8) = make_uint4(v2.x, v2.y, v3.x, v3.y);
}

// ---------------- ring-3 counted-vmcnt GEMM v2: BM=256, per-wave 64x(BN/2) ----------------
// Tile 256xBN (BN 192 or 128), BK=32/phase, 8 waves as 4m x 2n, per-wave out 64x(BN/2):
// 4 A-frags + NF B-frags = 4+NF ds_reads feed 4*NF MFMAs (BN=192: 10 reads -> 24 MFMAs,
// 2458 FLOP/lane-byte = 1.4x round-14's 1755 -> LDS pipe drops below MFMA time).
// Staging per chunk: A 16 instrs (2/wave), B BN/16 instrs (BN=192: waves 0-3 x2, 4-7 x1;
// BN=128: 1/wave). Per-wave loads/stage: 4 or 3 -> uniform vmcnt(3) is exact for 3-load
// waves, 1-load-stricter for 4-load waves (never drains; in-order vmcnt retire).
// Ring-3 race-free as before (slot(t+2) == slot(t-1), readers done at barrier-t).
// Grid = (M/256)*(N/BN) = 256 = exactly 1 block/CU (deterministic CU load).
// Swizzle (rule #21): linear LDS dest; global chunk (l&3)^((l>>3)&3); read chunk g^((c16>>1)&3).
template<int BN, typename OutT>
__global__ __launch_bounds__(512, 2) void gemm_ring2_kernel(const bf16_t* __restrict__ A,
                                                            const bf16_t* __restrict__ Bt,
                                                            OutT* __restrict__ C,
                                                            int M, int N, int K) {
    constexpr int NF = BN / 32;          // per-wave col frags (6 for 192, 4 for 128)
    __shared__ bf16_t As[3][256 * 32];
    __shared__ bf16_t Bs[3][BN * 32];
    const int tid = threadIdx.x;
    const int lane = tid & 63, w = tid >> 6;
    const int wm = w >> 1, wn = w & 1;
    const int g = lane >> 4, c16 = lane & 15;
    const int srow = lane >> 2;                              // row within a 16-row DMA instr
    const int scg = ((lane & 3) ^ ((lane >> 3) & 3)) * 8;    // pre-swizzled global chunk (elems)
    const int rdc = (g ^ ((c16 >> 1) & 3)) * 8;              // swizzled read chunk (elems)

    // XCD swizzle, bm-fastest
    const int nbm = M / 256;
    const int cpx = gridDim.x >> 3;
    const int bid = blockIdx.x;
    const int swz = (bid & 7) * cpx + (bid >> 3);
    const int bm = swz % nbm, bn = swz / nbm;

    const bf16_t* Ab = A + (size_t)(bm * 256) * K;
    const bf16_t* Bb = Bt + (size_t)bn * BN * K;

    auto stage = [&](int slot, int kt) {
        const bf16_t* Ak = Ab + (size_t)kt * 32;
        const bf16_t* Bk = Bb + (size_t)kt * 32;
#pragma unroll
        for (int j = 0; j < 2; ++j) {    // A: 16 instrs, 2/wave (rows 32w..32w+31)
            int rb = 32 * w + 16 * j;
            gload_lds16(Ak + (size_t)(rb + srow) * K + scg, &As[slot][rb * 32]);
        }
        if constexpr (BN == 192) {       // B: 12 instrs: waves 0-3 x2, waves 4-7 x1
            if (w < 4) {
#pragma unroll
                for (int j = 0; j < 2; ++j) {
                    int rb = 32 * w + 16 * j;
                    gload_lds16(Bk + (size_t)(rb + srow) * K + scg, &Bs[slot][rb * 32]);
                }
            } else {
                int rb = 128 + 16 * (w - 4);
                gload_lds16(Bk + (size_t)(rb + srow) * K + scg, &Bs[slot][rb * 32]);
            }
        } else {                         // BN==128: B 8 instrs, 1/wave
            int rb = 16 * w;
            gload_lds16(Bk + (size_t)(rb + srow) * K + scg, &Bs[slot][rb * 32]);
        }
    };

    f32x4 acc[4][NF];
#pragma unroll
    for (int i = 0; i < 4; ++i)
#pragma unroll
        for (int j = 0; j < NF; ++j)
            acc[i][j] = (f32x4){0.f, 0.f, 0.f, 0.f};

    const int NT = K / 32;
    stage(0, 0);
    stage(1, 1);

    int slot = 0, slot2 = 2;             // slot = t%3, slot2 = (t+2)%3
    for (int t = 0; t < NT; ++t) {
        asm volatile("s_waitcnt vmcnt(3)" ::: "memory");
        __builtin_amdgcn_s_barrier();
        __builtin_amdgcn_sched_barrier(0);
        __builtin_amdgcn_s_setprio(1);

        bf16x8 af[4], bf[NF];
#pragma unroll
        for (int i = 0; i < 4; ++i) {
            int arow = wm * 64 + i * 16 + c16;
            af[i] = *(const bf16x8*)&As[slot][arow * 32 + rdc];
        }
#pragma unroll
        for (int j = 0; j < NF; ++j) {
            int brow = wn * (BN / 2) + j * 16 + c16;
            bf[j] = *(const bf16x8*)&Bs[slot][brow * 32 + rdc];
        }
        int nk = t + 2;
        if (nk >= NT) nk -= NT;          // wrap-stage: keeps ledger uniform, never read
        stage(slot2, nk);

        // NO lgkmcnt(0) fence: compiler interleaves ds_reads with MFMAs (counted lgkmcnt)
#pragma unroll
        for (int i = 0; i < 4; ++i)
#pragma unroll
            for (int j = 0; j < NF; ++j)
                acc[i][j] = __builtin_amdgcn_mfma_f32_16x16x32_bf16(af[i], bf[j], acc[i][j], 0, 0, 0);
        __builtin_amdgcn_s_setprio(0);

        slot = (slot + 1) % 3;
        slot2 = (slot2 + 1) % 3;
    }

#pragma unroll
    for (int mi = 0; mi < 4; ++mi)
#pragma unroll
        for (int ni = 0; ni < NF; ++ni) {
            int col = bn * BN + wn * (BN / 2) + ni * 16 + c16;
#pragma unroll
            for (int r = 0; r < 4; ++r) {
                int row = bm * 256 + wm * 64 + mi * 16 + g * 4 + r;
                C[(size_t)row * N + col] = (OutT)acc[mi][ni][r];
            }
        }
}

// ---------------- RoPE: in bf16 [S][ld] (head block at col h*128) -> out bf16 [H][S][128] ----------------
__global__ void rope_kernel(const bf16_t* __restrict__ in, bf16_t* __restrict__ out,
                            const int* __restrict__ pos, int H, int ld, float scale) {
    int idx = blockIdx.x * blockDim.x + threadIdx.x;
    int total = S_LEN * H * 64;
    if (idx >= total) return;
    int d = idx & 63;
    int h = (idx >> 6) % H;
    int s = idx / (64 * H);
    const bf16_t* base = in + (size_t)s * ld + h * HD;
    float x0 = (float)base[d], x1 = (float)base[d + 64];
    float p = (float)pos[s];
    float invf = fast_exp2(-0.20762050593046935f * (float)d);  // log2(10000)/64
    float f = p * invf;
    float sn, cs;
    __sincosf(f, &sn, &cs);
    float o0 = (x0 * cs - x1 * sn) * scale;
    float o1 = (x1 * cs + x0 * sn) * scale;
    bf16_t* ob = out + ((size_t)h * S_LEN + s) * HD;
    ob[d] = (bf16_t)o0;
    ob[d + 64] = (bf16_t)o1;
}

// ---------------- flash attention v5 (unchanged from round 15) ----------------
#define PLD 68
__global__ __launch_bounds__(512) void attn_kernel(const bf16_t* __restrict__ Q,
                                                   const bf16_t* __restrict__ K,
                                                   const bf16_t* __restrict__ Vt,
                                                   bf16_t* __restrict__ O) {
    __shared__ bf16_t Ks[4][64 * 128];   // [kv row][d], swizzled chunks
    __shared__ bf16_t Vs[4][128 * 64];   // [d][kv], swizzled chunks
    __shared__ bf16_t Pl[8][16 * PLD];
    const int tid = threadIdx.x;
    const int lane = tid & 63, w = tid >> 6;   // w: 0..7
    const int bid = blockIdx.x;
    const int h = bid & 31;
    const int x = bid >> 5;              // 0..7
    const int grp = w >> 2, wi = w & 3;
    const int kv = h >> 2;               // N_REP = 4
    const int quad = lane >> 4, c16 = lane & 15;
    const int c7 = c16 & 7;
    const bf16_t* Qh = Q + (size_t)h * S_LEN * HD;
    const bf16_t* Kh = K + (size_t)kv * S_LEN * HD;
    const bf16_t* Vh = Vt + (size_t)kv * HD * S_LEN;
    bf16_t* P = Pl[w];

    auto stage = [&](int slot, int kb) {
        bf16_t* Kd = Ks[slot];
        bf16_t* Vd = Vs[slot];
#pragma unroll
        for (int j = 0; j < 2; ++j) {
            int i = w * 2 + j;           // 16 instrs across 8 waves
            {   // K: instr covers 4 rows of 256B
                int row = 4 * i + (lane >> 4);
                int sc = (lane & 15) ^ (row & 7);
                gload_lds16(Kh + (size_t)(kb + row) * HD + sc * 8, Kd + i * 512);
            }
            {   // V: instr covers 8 rows of 128B
                int row = 8 * i + (lane >> 3);
                int sc = (lane & 7) ^ ((lane >> 3) & 7);
                gload_lds16(Vh + (size_t)row * S_LEN + kb + sc * 8, Vd + i * 512);
            }
        }
    };

    bf16x8 ones;
#pragma unroll
    for (int j = 0; j < 8; ++j) ones[j] = (bf16_t)1.0f;

    for (int ph = 0; ph < 2; ++ph) {
        const int qt = (ph == 0) ? x : 15 - x;
        const int R = qt + 1;            // rounds for this q-tile
        const int qb = qt * 128 + wi * 32;

        bf16x8 qf[2][4];
#pragma unroll
        for (int rg = 0; rg < 2; ++rg)
#pragma unroll
            for (int c = 0; c < 4; ++c)
                qf[rg][c] = *(const bf16x8*)(Qh + (size_t)(qb + rg * 16 + c16) * HD + c * 32 + quad * 8);

        f32x4 acc_o[2][8];
#pragma unroll
        for (int rg = 0; rg < 2; ++rg)
#pragma unroll
            for (int dt = 0; dt < 8; ++dt) acc_o[rg][dt] = (f32x4){0.f, 0.f, 0.f, 0.f};
        f32x4 acc_l[2] = {(f32x4){0.f, 0.f, 0.f, 0.f}, (f32x4){0.f, 0.f, 0.f, 0.f}};
        float m[2][4];
#pragma unroll
        for (int rg = 0; rg < 2; ++rg)
#pragma unroll
            for (int r = 0; r < 4; ++r) m[rg][r] = -1e30f;

        stage(0, 0);
        stage(1, 64);
        __syncthreads();

        for (int r = 0; r < R; ++r) {
            int jn0 = 2 * r + 2, jn1 = 2 * r + 3;
            if (jn0 < 2 * R) stage(jn0 & 3, jn0 * 64);
            if (jn1 < 2 * R) stage(jn1 & 3, jn1 * 64);

            const int j = 2 * r + grp;   // this group's kv tile
            const int kb = j * 64;
            const bf16_t* Kb = Ks[j & 3];
            const bf16_t* Vb = Vs[j & 3];

            if (kb <= qb + 31) {         // wave-active
                const bool diag = (kb + 63 > qb);

                f32x4 sacc[2][4];
#pragma unroll
                for (int rg = 0; rg < 2; ++rg)
#pragma unroll
                    for (int t = 0; t < 4; ++t) sacc[rg][t] = (f32x4){0.f, 0.f, 0.f, 0.f};
#pragma unroll
                for (int t = 0; t < 4; ++t) {
                    const bf16_t* krow = Kb + (t * 16 + c16) * 128;
#pragma unroll
                    for (int cc = 0; cc < 4; ++cc) {
                        bf16x8 kf = *(const bf16x8*)(krow + (((cc * 4 + quad) ^ c7) * 8));
                        sacc[0][t] = __builtin_amdgcn_mfma_f32_16x16x32_bf16(qf[0][cc], kf, sacc[0][t], 0, 0, 0);
                        sacc[1][t] = __builtin_amdgcn_mfma_f32_16x16x32_bf16(qf[1][cc], kf, sacc[1][t], 0, 0, 0);
                    }
                }
                bf16x8 pf[2][2];
#pragma unroll
                for (int rg = 0; rg < 2; ++rg) {
                    float p[4][4], mxr[4];
#pragma unroll
                    for (int r4 = 0; r4 < 4; ++r4) {
                        int qq = qb + rg * 16 + quad * 4 + r4;
#pragma unroll
                        for (int t = 0; t < 4; ++t) {
                            float sv = sacc[rg][t][r4];
                            if (diag && (kb + t * 16 + c16 > qq)) sv = -1e30f;
                            p[t][r4] = sv;
                        }
                        float mx = fmaxf(fmaxf(p[0][r4], p[1][r4]), fmaxf(p[2][r4], p[3][r4]));
                        mx = fmaxf(mx, __shfl_xor(mx, 1));
                        mx = fmaxf(mx, __shfl_xor(mx, 2));
                        mx = fmaxf(mx, __shfl_xor(mx, 4));
                        mx = fmaxf(mx, __shfl_xor(mx, 8));
                        mxr[r4] = mx;
                    }
                    bool resc = false;
#pragma unroll
                    for (int r4 = 0; r4 < 4; ++r4) resc = resc || (mxr[r4] > m[rg][r4] + 8.f);
                    if (__any(resc)) {
#pragma unroll
                        for (int r4 = 0; r4 < 4; ++r4) {
                            float mn = fmaxf(m[rg][r4], mxr[r4]);
                            float al = fast_exp2(m[rg][r4] - mn);
                            m[rg][r4] = mn;
                            acc_l[rg][r4] *= al;
#pragma unroll
                            for (int dt = 0; dt < 8; ++dt) acc_o[rg][dt][r4] *= al;
                        }
                    }
#pragma unroll
                    for (int r4 = 0; r4 < 4; ++r4)
#pragma unroll
                        for (int t = 0; t < 4; ++t)
                            p[t][r4] = fast_exp2(p[t][r4] - m[rg][r4]);
#pragma unroll
                    for (int t = 0; t < 4; ++t)
#pragma unroll
                        for (int r4 = 0; r4 < 4; ++r4)
                            P[(quad * 4 + r4) * PLD + t * 16 + c16] = (bf16_t)p[t][r4];
                    pf[rg][0] = *(const bf16x8*)(P + c16 * PLD + quad * 8);
                    pf[rg][1] = *(const bf16x8*)(P + c16 * PLD + 32 + quad * 8);
                }
                acc_l[0] = __builtin_amdgcn_mfma_f32_16x16x32_bf16(pf[0][0], ones, acc_l[0], 0, 0, 0);
                acc_l[0] = __builtin_amdgcn_mfma_f32_16x16x32_bf16(pf[0][1], ones, acc_l[0], 0, 0, 0);
                acc_l[1] = __builtin_amdgcn_mfma_f32_16x16x32_bf16(pf[1][0], ones, acc_l[1], 0, 0, 0);
                acc_l[1] = __builtin_amdgcn_mfma_f32_16x16x32_bf16(pf[1][1], ones, acc_l[1], 0, 0, 0);
#pragma unroll
                for (int dt = 0; dt < 8; ++dt) {
                    const bf16_t* vrow = Vb + (dt * 16 + c16) * 64;
                    bf16x8 vf0 = *(const bf16x8*)(vrow + ((quad ^ c7) * 8));
                    bf16x8 vf1 = *(const bf16x8*)(vrow + (((4 + quad) ^ c7) * 8));
                    acc_o[0][dt] = __builtin_amdgcn_mfma_f32_16x16x32_bf16(pf[0][0], vf0, acc_o[0][dt], 0, 0, 0);
                    acc_o[0][dt] = __builtin_amdgcn_mfma_f32_16x16x32_bf16(pf[0][1], vf1, acc_o[0][dt], 0, 0, 0);
                    acc_o[1][dt] = __builtin_amdgcn_mfma_f32_16x16x32_bf16(pf[1][0], vf0, acc_o[1][dt], 0, 0, 0);
                    acc_o[1][dt] = __builtin_amdgcn_mfma_f32_16x16x32_bf16(pf[1][1], vf1, acc_o[1][dt], 0, 0, 0);
                }
            }
            __syncthreads();
        }

        // ---- merge the two kv-split groups (grp1 -> LDS, grp0 combines & writes O) ----
        float* s0 = (float*)&Ks[0][0];   // 48 idx x 256 x 4B = 49KB <= 64KB
        float* s1 = (float*)&Vs[0][0];   // 32 idx x 256 x 4B = 32KB <= 64KB
        const int sl = wi * 64 + lane;
        if (grp == 1) {
#pragma unroll
            for (int rg = 0; rg < 2; ++rg)
#pragma unroll
                for (int r4 = 0; r4 < 4; ++r4) {
                    s0[(rg * 4 + r4) * 256 + sl] = m[rg][r4];
                    s0[(8 + rg * 4 + r4) * 256 + sl] = acc_l[rg][r4];
                }
#pragma unroll
            for (int dt = 0; dt < 8; ++dt)
#pragma unroll
                for (int r4 = 0; r4 < 4; ++r4) {
                    s0[(16 + dt * 4 + r4) * 256 + sl] = acc_o[0][dt][r4];
                    s1[(dt * 4 + r4) * 256 + sl] = acc_o[1][dt][r4];
                }
        }
        __syncthreads();
        if (grp == 0) {
#pragma unroll
            for (int rg = 0; rg < 2; ++rg)
#pragma unroll
                for (int r4 = 0; r4 < 4; ++r4) {
                    float m1 = s0[(rg * 4 + r4) * 256 + sl];
                    float l1 = s0[(8 + rg * 4 + r4) * 256 + sl];
                    float mm = fmaxf(m[rg][r4], m1);
                    float a0 = fast_exp2(m[rg][r4] - mm);
                    float a1 = fast_exp2(m1 - mm);
                    float ll = acc_l[rg][r4] * a0 + l1 * a1;
                    float inv = 1.f / ll;
                    bf16_t* orow = &O[(size_t)(qb + rg * 16 + quad * 4 + r4) * HIDDEN + h * HD];
#pragma unroll
                    for (int dt = 0; dt < 8; ++dt) {
                        float o1 = (rg == 0) ? s0[(16 + dt * 4 + r4) * 256 + sl]
                                             : s1[(dt * 4 + r4) * 256 + sl];
                        float val = (acc_o[rg][dt][r4] * a0 + o1 * a1) * inv;
                        orow[dt * 16 + c16] = (bf16_t)val;
                    }
                }
        }
        __syncthreads();                 // scratch free before next q-tile's staging
    }
}

// ---------------- host ----------------
extern "C" void kernel_launch(void* const* d_in, const int* in_sizes, int n_in,
                              void* d_out, int out_size, void* d_ws, size_t ws_size,
                              hipStream_t stream) {
    const float* hs = (const float*)d_in[0];
    const float* Wq = (const float*)d_in[1];
    const float* Wk = (const float*)d_in[2];
    const float* Wv = (const float*)d_in[3];
    const float* Wo = (const float*)d_in[4];
    const int* pos = (const int*)d_in[6];
    float* out = (float*)d_out;

    char* ws = (char*)d_ws;
    size_t off = 0;
    auto alloc = [&](size_t bytes) -> void* {
        void* p = ws + off;
        off += (bytes + 255) & ~(size_t)255;
        return p;
    };
    bf16_t* hB    = (bf16_t*)alloc((size_t)S_LEN * HIDDEN * 2);
    bf16_t* WqkvT = (bf16_t*)alloc((size_t)NQKV * HIDDEN * 2);   // [6144][4096]
    bf16_t* WoT   = (bf16_t*)alloc((size_t)HIDDEN * HIDDEN * 2);
    bf16_t* QKV   = (bf16_t*)alloc((size_t)S_LEN * NQKV * 2);    // [2048][6144] bf16
    bf16_t* Qr    = (bf16_t*)alloc((size_t)NH * S_LEN * HD * 2);
    bf16_t* Kr    = (bf16_t*)alloc((size_t)NKV * S_LEN * HD * 2);
    bf16_t* Vt    = (bf16_t*)alloc((size_t)NKV * HD * S_LEN * 2);
    bf16_t* Oat   = (bf16_t*)alloc((size_t)S_LEN * HIDDEN * 2);

    // 1. cast hidden to bf16
    cast_bf16_kernel<<<2048, 256, 0, stream>>>(hs, hB, S_LEN * HIDDEN / 4);
    // 2. transpose-cast weights into fused [6144][4096] (64x64 tiles, vectorized)
    transpose_cast_kernel<<<dim3(HIDDEN / 64, HIDDEN / 64), 256, 0, stream>>>(Wq, WqkvT, HIDDEN, HIDDEN);
    transpose_cast_kernel<<<dim3(1024 / 64, HIDDEN / 64), 256, 0, stream>>>(Wk, WqkvT + (size_t)4096 * HIDDEN, 1024, HIDDEN);
    transpose_cast_kernel<<<dim3(1024 / 64, HIDDEN / 64), 256, 0, stream>>>(Wv, WqkvT + (size_t)5120 * HIDDEN, 1024, HIDDEN);
    transpose_cast_kernel<<<dim3(HIDDEN / 64, HIDDEN / 64), 256, 0, stream>>>(Wo, WoT, HIDDEN, HIDDEN);
    // 3. fused QKV projection -> bf16 [2048][6144]; 256x192 tile -> 256 blocks = 1/CU
    gemm_ring2_kernel<192, bf16_t><<<(S_LEN / 256) * (NQKV / 192), 512, 0, stream>>>(hB, WqkvT, QKV, S_LEN, NQKV, HIDDEN);
    // 4. RoPE; Q scale = log2(e)/sqrt(128) for exp2-domain softmax
    rope_kernel<<<(S_LEN * NH * 64 + 255) / 256, 256, 0, stream>>>(QKV, Qr, pos, NH, NQKV, 0.1275174310f);
    rope_kernel<<<(S_LEN * NKV * 64 + 255) / 256, 256, 0, stream>>>(QKV + 4096, Kr, pos, NKV, NQKV, 1.0f);
    // 5. V transpose: bf16 [S][1024] (stride 6144) -> [1024][2048] == [NKV][128][S]
    transpose_bf16_kernel<<<dim3(1024 / 64, S_LEN / 64), 256, 0, stream>>>(QKV + 5120, Vt, NQKV, S_LEN);
    // 6. flash attention v5: 256 blocks, 1/CU, 17 uniform rounds
    attn_kernel<<<256, 512, 0, stream>>>(Qr, Kr, Vt, Oat);
    // 7. output projection (fp32 out); 256x128 tile -> 256 blocks = 1/CU
    gemm_ring2_kernel<128, float><<<(S_LEN / 256) * (HIDDEN / 128), 512, 0, stream>>>(Oat, WoT, out, S_LEN, HIDDEN, HIDDEN);
}